// Round 3
// baseline (1355.682 us; speedup 1.0000x reference)
//
#include <hip/hip_runtime.h>

#define NN 8192
#define EE 262144
#define TT 256
#define HH 2048
#define OO 1024
#define LL 128

typedef __bf16 bf16_t;
typedef __bf16 bf16x8_t __attribute__((ext_vector_type(8)));
typedef float f32x4_t __attribute__((ext_vector_type(4)));

// ---------------- CSR build (dst-major) ----------------
__global__ __launch_bounds__(256) void count_deg_kernel(const int* __restrict__ dst,
                                                        int* __restrict__ deg) {
  int e = blockIdx.x * 256 + threadIdx.x;
  if (e < EE) atomicAdd(&deg[dst[e]], 1);
}

__global__ __launch_bounds__(1024) void scan_kernel(const int* __restrict__ deg,
                                                    int* __restrict__ rs) {
  __shared__ int s[1024];
  int t = threadIdx.x;
  int pre[8];
  int sum = 0;
#pragma unroll
  for (int j = 0; j < 8; ++j) { pre[j] = sum; sum += deg[t * 8 + j]; }
  s[t] = sum;
  __syncthreads();
  for (int off = 1; off < 1024; off <<= 1) {
    int add = (t >= off) ? s[t - off] : 0;
    __syncthreads();
    s[t] += add;
    __syncthreads();
  }
  int base = (t == 0) ? 0 : s[t - 1];
#pragma unroll
  for (int j = 0; j < 8; ++j) rs[t * 8 + j] = base + pre[j];
  if (t == 1023) rs[8192] = s[1023];
}

__global__ __launch_bounds__(256) void fill_csr_kernel(const int* __restrict__ src,
                                                       const int* __restrict__ dst,
                                                       const int* __restrict__ rs,
                                                       int* __restrict__ cur,
                                                       int* __restrict__ csr) {
  int e = blockIdx.x * 256 + threadIdx.x;
  if (e >= EE) return;
  int d = dst[e];
  int p = atomicAdd(&cur[d], 1);
  csr[rs[d] + p] = src[e];
}

// ------- layer-0 aggregation: f32 input, bf16 output. out[i] = x[i] + sum_j x[src] -------
__global__ __launch_bounds__(64) void agg_f32_kernel(const float* __restrict__ x,
                                                     bf16_t* __restrict__ out,
                                                     const int* __restrict__ rs,
                                                     const int* __restrict__ csr) {
  int node = blockIdx.x;
  int c = threadIdx.x;           // 32 chunks of 8 elems over d=256
  if (c >= 32) return;
  const f32x4_t* xv = (const f32x4_t*)x;
  size_t base = (size_t)node * 64 + c * 2;  // in float4 units (64 per row)
  f32x4_t a0 = xv[base], a1 = xv[base + 1];
  int e0 = rs[node], e1 = rs[node + 1];
  for (int e = e0; e < e1; ++e) {
    size_t sb = (size_t)csr[e] * 64 + c * 2;
    f32x4_t v0 = xv[sb], v1 = xv[sb + 1];
#pragma unroll
    for (int j = 0; j < 4; ++j) { a0[j] += v0[j]; a1[j] += v1[j]; }
  }
  bf16x8_t o;
#pragma unroll
  for (int j = 0; j < 4; ++j) { o[j] = (bf16_t)a0[j]; o[4 + j] = (bf16_t)a1[j]; }
  ((bf16x8_t*)out)[(size_t)node * 32 + c] = o;
}

// ------- aggregation: bf16 input/output, f32 accumulate -------
__global__ __launch_bounds__(256) void agg_bf16_kernel(const bf16_t* __restrict__ x,
                                                       bf16_t* __restrict__ out,
                                                       const int* __restrict__ rs,
                                                       const int* __restrict__ csr, int d) {
  int node = blockIdx.x;
  int c = threadIdx.x;
  int nch = d >> 3;
  if (c >= nch) return;
  const bf16x8_t* xv = (const bf16x8_t*)x;
  bf16x8_t self = xv[(size_t)node * nch + c];
  float acc[8];
#pragma unroll
  for (int j = 0; j < 8; ++j) acc[j] = (float)self[j];
  int e0 = rs[node], e1 = rs[node + 1];
  for (int e = e0; e < e1; ++e) {
    bf16x8_t v = xv[(size_t)csr[e] * nch + c];
#pragma unroll
    for (int j = 0; j < 8; ++j) acc[j] += (float)v[j];
  }
  bf16x8_t o;
#pragma unroll
  for (int j = 0; j < 8; ++j) o[j] = (bf16_t)acc[j];
  ((bf16x8_t*)out)[(size_t)node * nch + c] = o;
}

// ---------------- transpose + cast: f32 [K,N] -> bf16 [N,K] ----------------
__global__ __launch_bounds__(256) void transpose_cast_kernel(const float* __restrict__ in,
                                                             bf16_t* __restrict__ out,
                                                             int K, int N) {
  __shared__ float tile[64][65];
  int n0 = blockIdx.x * 64, k0 = blockIdx.y * 64;
  int t = threadIdx.x;
  for (int c = t; c < 1024; c += 256) {      // 64 rows x 16 float4 chunks
    int r = c >> 4, col = (c & 15) * 4;
    f32x4_t v = *(const f32x4_t*)&in[(size_t)(k0 + r) * N + n0 + col];
#pragma unroll
    for (int j = 0; j < 4; ++j) tile[r][col + j] = v[j];
  }
  __syncthreads();
  for (int c = t; c < 512; c += 256) {       // 64 n-rows x 8 bf16x8 chunks
    int r = c >> 3, col = (c & 7) * 8;       // r: n-index, col: k-base
    bf16x8_t v;
#pragma unroll
    for (int j = 0; j < 8; ++j) v[j] = (bf16_t)tile[col + j][r];
    *(bf16x8_t*)&out[(size_t)(n0 + r) * K + k0 + col] = v;
  }
}

// ------- GEMM: C[M,N] = A[M,K] @ Bt[N,K]^T + bias(f32) [+relu], bf16 MFMA, f32 acc -------
// 128x128 tile, BK=32, 256 threads = 4 waves, each wave 64x64 via 4x4 mfma_f32_16x16x32_bf16.
template <bool F32OUT>
__global__ __launch_bounds__(256) void gemm_bt_kernel(
    const bf16_t* __restrict__ A, const bf16_t* __restrict__ Bt,
    const float* __restrict__ bias, void* __restrict__ Cv,
    int M, int N, int K, int relu) {
  __shared__ __align__(16) bf16_t lA[128 * 32];
  __shared__ __align__(16) bf16_t lB[128 * 32];
  const int tid = threadIdx.x;
  const int lane = tid & 63;
  const int wave = tid >> 6;
  const int wm64 = (wave & 1) * 64;
  const int wn64 = (wave >> 1) * 64;
  const int row16 = lane & 15;
  const int quad = lane >> 4;
  const size_t m0 = (size_t)blockIdx.y * 128;
  const size_t n0 = (size_t)blockIdx.x * 128;

  f32x4_t acc[4][4];
#pragma unroll
  for (int i = 0; i < 4; ++i)
#pragma unroll
    for (int j = 0; j < 4; ++j)
#pragma unroll
      for (int r = 0; r < 4; ++r) acc[i][j][r] = 0.f;

  const bf16_t* Abase = A + m0 * K;
  const bf16_t* Bbase = Bt + n0 * K;
  // chunk c (0..511): row = c>>2, kcol = (c&3)*8 ; thread owns c = tid, tid+256
  const int r0 = tid >> 2;
  const int r1 = (tid + 256) >> 2;
  const int kc = (tid & 3) * 8;

  for (int kt = 0; kt < K; kt += 32) {
    bf16x8_t ga0 = *(const bf16x8_t*)(Abase + (size_t)r0 * K + kt + kc);
    bf16x8_t ga1 = *(const bf16x8_t*)(Abase + (size_t)r1 * K + kt + kc);
    bf16x8_t gb0 = *(const bf16x8_t*)(Bbase + (size_t)r0 * K + kt + kc);
    bf16x8_t gb1 = *(const bf16x8_t*)(Bbase + (size_t)r1 * K + kt + kc);
    __syncthreads();  // previous iteration's fragment reads complete
    *(bf16x8_t*)&lA[tid * 8] = ga0;
    *(bf16x8_t*)&lA[(tid + 256) * 8] = ga1;
    *(bf16x8_t*)&lB[tid * 8] = gb0;
    *(bf16x8_t*)&lB[(tid + 256) * 8] = gb1;
    __syncthreads();
    bf16x8_t af[4], bfr[4];
#pragma unroll
    for (int i = 0; i < 4; ++i)
      af[i] = *(const bf16x8_t*)&lA[(wm64 + i * 16 + row16) * 32 + quad * 8];
#pragma unroll
    for (int i = 0; i < 4; ++i)
      bfr[i] = *(const bf16x8_t*)&lB[(wn64 + i * 16 + row16) * 32 + quad * 8];
#pragma unroll
    for (int i = 0; i < 4; ++i)
#pragma unroll
      for (int j = 0; j < 4; ++j)
        acc[i][j] = __builtin_amdgcn_mfma_f32_16x16x32_bf16(af[i], bfr[j], acc[i][j], 0, 0, 0);
  }

  // C/D layout: col = lane&15, row = quad*4 + reg  [verified m89/m91]
#pragma unroll
  for (int i = 0; i < 4; ++i) {
    size_t row = m0 + wm64 + i * 16 + quad * 4;
#pragma unroll
    for (int j = 0; j < 4; ++j) {
      int col = (int)n0 + wn64 + j * 16 + row16;
      float b = bias[col];
#pragma unroll
      for (int r = 0; r < 4; ++r) {
        float o = acc[i][j][r] + b;
        if (relu) o = fmaxf(o, 0.f);
        if (F32OUT)
          ((float*)Cv)[(row + r) * (size_t)N + col] = o;
        else
          ((bf16_t*)Cv)[(row + r) * (size_t)N + col] = (bf16_t)o;
      }
    }
  }
}

// ---------------- z = mean + var*eps (f32) ----------------
__global__ __launch_bounds__(256) void reparam_kernel(const float* __restrict__ mean,
                                                      const float* __restrict__ var,
                                                      const float* __restrict__ eps,
                                                      float* __restrict__ z) {
  int i = blockIdx.x * 256 + threadIdx.x;  // float4 chunk over NN*LL/4
  f32x4_t m = ((const f32x4_t*)mean)[i];
  f32x4_t v = ((const f32x4_t*)var)[i];
  f32x4_t e = ((const f32x4_t*)eps)[i];
  f32x4_t o;
#pragma unroll
  for (int j = 0; j < 4; ++j) o[j] = m[j] + v[j] * e[j];
  ((f32x4_t*)z)[i] = o;
}

extern "C" void kernel_launch(void* const* d_in, const int* in_sizes, int n_in,
                              void* d_out, int out_size, void* d_ws, size_t ws_size,
                              hipStream_t stream) {
  (void)in_sizes; (void)n_in; (void)out_size; (void)ws_size;
  const float* x0 = (const float*)d_in[0];
  const int* ei = (const int*)d_in[1];
  const int* src = ei;
  const int* dst = ei + EE;
  const float* w1[4] = {(const float*)d_in[2], (const float*)d_in[6],
                        (const float*)d_in[10], (const float*)d_in[14]};
  const float* b1[4] = {(const float*)d_in[3], (const float*)d_in[7],
                        (const float*)d_in[11], (const float*)d_in[15]};
  const float* w2[4] = {(const float*)d_in[4], (const float*)d_in[8],
                        (const float*)d_in[12], (const float*)d_in[16]};
  const float* b2[4] = {(const float*)d_in[5], (const float*)d_in[9],
                        (const float*)d_in[13], (const float*)d_in[17]};
  const float* wm = (const float*)d_in[18];
  const float* bm = (const float*)d_in[19];
  const float* wv = (const float*)d_in[20];
  const float* bv = (const float*)d_in[21];
  const float* eps = (const float*)d_in[22];
  float* out = (float*)d_out;

  // ws layout (bytes): B0 32M | B1 32M | WT(bf16) 8M | deg 32K | cur 32K | rs | csr 1M  (~73.2 MB)
  char* ws = (char*)d_ws;
  bf16_t* B0 = (bf16_t*)(ws);
  bf16_t* B1 = (bf16_t*)(ws + 33554432);
  bf16_t* WT = (bf16_t*)(ws + 67108864);
  int* deg = (int*)(ws + 75497472);
  int* cur = deg + 8192;
  int* rs = deg + 16384;       // 8193 ints (+pad)
  int* csr = deg + 16384 + 8200;

  hipMemsetAsync(deg, 0, 2 * 8192 * sizeof(int), stream);
  count_deg_kernel<<<EE / 256, 256, 0, stream>>>(dst, deg);
  scan_kernel<<<1, 1024, 0, stream>>>(deg, rs);
  fill_csr_kernel<<<EE / 256, 256, 0, stream>>>(src, dst, rs, cur, csr);

  auto T = [&](const float* w, int K, int Nn) {
    transpose_cast_kernel<<<dim3(Nn / 64, K / 64), 256, 0, stream>>>(w, WT, K, Nn);
  };
  auto G = [&](const bf16_t* A, const float* bias, bf16_t* C, int M, int Nn, int K, int relu) {
    gemm_bt_kernel<false><<<dim3(Nn / 128, M / 128), 256, 0, stream>>>(A, WT, bias, (void*)C, M, Nn, K, relu);
  };
  auto GF = [&](const bf16_t* A, const float* bias, float* C, int M, int Nn, int K) {
    gemm_bt_kernel<true><<<dim3(Nn / 128, M / 128), 256, 0, stream>>>(A, WT, bias, (void*)C, M, Nn, K, 0);
  };

  // Layer 0: x0 f32 [N,256] -> agg bf16 (B1) -> h (B0) -> x1 (B1)
  agg_f32_kernel<<<NN, 64, 0, stream>>>(x0, B1, rs, csr);
  T(w1[0], TT, HH); G(B1, b1[0], B0, NN, HH, TT, 1);
  T(w2[0], HH, HH); G(B0, b2[0], B1, NN, HH, HH, 1);
  // Layer 1: x1 (B1) -> x2 (B0)
  agg_bf16_kernel<<<NN, 256, 0, stream>>>(B1, B0, rs, csr, HH);
  T(w1[1], HH, HH); G(B0, b1[1], B1, NN, HH, HH, 1);
  T(w2[1], HH, HH); G(B1, b2[1], B0, NN, HH, HH, 1);
  // Layer 2: x2 (B0) -> x3 (B1)
  agg_bf16_kernel<<<NN, 256, 0, stream>>>(B0, B1, rs, csr, HH);
  T(w1[2], HH, HH); G(B1, b1[2], B0, NN, HH, HH, 1);
  T(w2[2], HH, HH); G(B0, b2[2], B1, NN, HH, HH, 1);
  // Layer 3: x3 (B1) -> x4 (B0) [N,1024], no relu after last conv
  agg_bf16_kernel<<<NN, 256, 0, stream>>>(B1, B0, rs, csr, HH);
  T(w1[3], HH, OO); G(B0, b1[3], B1, NN, OO, HH, 1);
  T(w2[3], OO, OO); G(B1, b2[3], B0, NN, OO, OO, 0);
  // Heads (f32 out): mean -> out[NL:2NL], var -> out[2NL:3NL]
  T(wm, OO, LL); GF(B0, bm, out + (size_t)NN * LL, NN, LL, OO);
  T(wv, OO, LL); GF(B0, bv, out + (size_t)2 * NN * LL, NN, LL, OO);
  // z = mean + var*eps -> out[0:NL]
  reparam_kernel<<<(NN * LL / 4) / 256, 256, 0, stream>>>(
      out + (size_t)NN * LL, out + (size_t)2 * NN * LL, eps, out);
}

// Round 4
// 1215.454 us; speedup vs baseline: 1.1154x; 1.1154x over previous
//
#include <hip/hip_runtime.h>

#define NN 8192
#define EE 262144
#define TT 256
#define HH 2048
#define OO 1024
#define LL 128

typedef __bf16 bf16_t;
typedef __bf16 bf16x8_t __attribute__((ext_vector_type(8)));
typedef float f32x4_t __attribute__((ext_vector_type(4)));

__device__ __forceinline__ void async16(void* lds, const void* g) {
  __builtin_amdgcn_global_load_lds(
      (const __attribute__((address_space(1))) void*)g,
      (__attribute__((address_space(3))) void*)lds, 16, 0, 0);
}

// ---------------- CSR build (dst-major) ----------------
__global__ __launch_bounds__(256) void count_deg_kernel(const int* __restrict__ dst,
                                                        int* __restrict__ deg) {
  int e = blockIdx.x * 256 + threadIdx.x;
  if (e < EE) atomicAdd(&deg[dst[e]], 1);
}

__global__ __launch_bounds__(1024) void scan_kernel(const int* __restrict__ deg,
                                                    int* __restrict__ rs) {
  __shared__ int s[1024];
  int t = threadIdx.x;
  int pre[8];
  int sum = 0;
#pragma unroll
  for (int j = 0; j < 8; ++j) { pre[j] = sum; sum += deg[t * 8 + j]; }
  s[t] = sum;
  __syncthreads();
  for (int off = 1; off < 1024; off <<= 1) {
    int add = (t >= off) ? s[t - off] : 0;
    __syncthreads();
    s[t] += add;
    __syncthreads();
  }
  int base = (t == 0) ? 0 : s[t - 1];
#pragma unroll
  for (int j = 0; j < 8; ++j) rs[t * 8 + j] = base + pre[j];
  if (t == 1023) rs[8192] = s[1023];
}

__global__ __launch_bounds__(256) void fill_csr_kernel(const int* __restrict__ src,
                                                       const int* __restrict__ dst,
                                                       const int* __restrict__ rs,
                                                       int* __restrict__ cur,
                                                       int* __restrict__ csr) {
  int e = blockIdx.x * 256 + threadIdx.x;
  if (e >= EE) return;
  int d = dst[e];
  int p = atomicAdd(&cur[d], 1);
  csr[rs[d] + p] = src[e];
}

// ---------------- cast f32 -> bf16 (vectorized) ----------------
__global__ __launch_bounds__(256) void cast_kernel(const float* __restrict__ in,
                                                   bf16_t* __restrict__ out) {
  int i = blockIdx.x * 256 + threadIdx.x;  // bf16x8 chunk over NN*TT/8
  f32x4_t a = ((const f32x4_t*)in)[i * 2];
  f32x4_t b = ((const f32x4_t*)in)[i * 2 + 1];
  bf16x8_t o;
#pragma unroll
  for (int j = 0; j < 4; ++j) { o[j] = (bf16_t)a[j]; o[4 + j] = (bf16_t)b[j]; }
  ((bf16x8_t*)out)[i] = o;
}

// ------- layer-0 aggregation, d=256 (32 chunks): 2 nodes per 64-thread block -------
__global__ __launch_bounds__(64) void agg0_kernel(const bf16_t* __restrict__ x,
                                                  bf16_t* __restrict__ out,
                                                  const int* __restrict__ rs,
                                                  const int* __restrict__ csr) {
  int t = threadIdx.x;
  int node = blockIdx.x * 2 + (t >> 5);
  int c = t & 31;
  const bf16x8_t* xv = (const bf16x8_t*)x;
  bf16x8_t self = xv[(size_t)node * 32 + c];
  float acc[8];
#pragma unroll
  for (int j = 0; j < 8; ++j) acc[j] = (float)self[j];
  int e0 = rs[node], e1 = rs[node + 1];
  int e = e0;
  for (; e + 4 <= e1; e += 4) {
    int s0 = csr[e], s1 = csr[e + 1], s2 = csr[e + 2], s3 = csr[e + 3];
    bf16x8_t v0 = xv[(size_t)s0 * 32 + c];
    bf16x8_t v1 = xv[(size_t)s1 * 32 + c];
    bf16x8_t v2 = xv[(size_t)s2 * 32 + c];
    bf16x8_t v3 = xv[(size_t)s3 * 32 + c];
#pragma unroll
    for (int j = 0; j < 8; ++j)
      acc[j] += (float)v0[j] + (float)v1[j] + (float)v2[j] + (float)v3[j];
  }
  for (; e < e1; ++e) {
    bf16x8_t v = xv[(size_t)csr[e] * 32 + c];
#pragma unroll
    for (int j = 0; j < 8; ++j) acc[j] += (float)v[j];
  }
  bf16x8_t o;
#pragma unroll
  for (int j = 0; j < 8; ++j) o[j] = (bf16_t)acc[j];
  ((bf16x8_t*)out)[(size_t)node * 32 + c] = o;
}

// ------- aggregation d=2048: bf16 in/out, f32 accumulate, 4x unrolled gathers -------
__global__ __launch_bounds__(256) void agg_bf16_kernel(const bf16_t* __restrict__ x,
                                                       bf16_t* __restrict__ out,
                                                       const int* __restrict__ rs,
                                                       const int* __restrict__ csr) {
  int node = blockIdx.x;
  int c = threadIdx.x;            // 256 chunks of 8
  const bf16x8_t* xv = (const bf16x8_t*)x;
  bf16x8_t self = xv[(size_t)node * 256 + c];
  float acc[8];
#pragma unroll
  for (int j = 0; j < 8; ++j) acc[j] = (float)self[j];
  int e0 = rs[node], e1 = rs[node + 1];
  int e = e0;
  for (; e + 4 <= e1; e += 4) {
    int s0 = csr[e], s1 = csr[e + 1], s2 = csr[e + 2], s3 = csr[e + 3];
    bf16x8_t v0 = xv[(size_t)s0 * 256 + c];
    bf16x8_t v1 = xv[(size_t)s1 * 256 + c];
    bf16x8_t v2 = xv[(size_t)s2 * 256 + c];
    bf16x8_t v3 = xv[(size_t)s3 * 256 + c];
#pragma unroll
    for (int j = 0; j < 8; ++j)
      acc[j] += (float)v0[j] + (float)v1[j] + (float)v2[j] + (float)v3[j];
  }
  for (; e < e1; ++e) {
    bf16x8_t v = xv[(size_t)csr[e] * 256 + c];
#pragma unroll
    for (int j = 0; j < 8; ++j) acc[j] += (float)v[j];
  }
  bf16x8_t o;
#pragma unroll
  for (int j = 0; j < 8; ++j) o[j] = (bf16_t)acc[j];
  ((bf16x8_t*)out)[(size_t)node * 256 + c] = o;
}

// ---------------- transpose + cast: f32 [K,N] -> bf16 [N,K] ----------------
__global__ __launch_bounds__(256) void transpose_cast_kernel(const float* __restrict__ in,
                                                             bf16_t* __restrict__ out,
                                                             int K, int N) {
  __shared__ float tile[64][65];
  int n0 = blockIdx.x * 64, k0 = blockIdx.y * 64;
  int t = threadIdx.x;
  for (int c = t; c < 1024; c += 256) {      // 64 rows x 16 float4 chunks
    int r = c >> 4, col = (c & 15) * 4;
    f32x4_t v = *(const f32x4_t*)&in[(size_t)(k0 + r) * N + n0 + col];
#pragma unroll
    for (int j = 0; j < 4; ++j) tile[r][col + j] = v[j];
  }
  __syncthreads();
  for (int c = t; c < 512; c += 256) {       // 64 n-rows x 8 bf16x8 chunks
    int r = c >> 3, col = (c & 7) * 8;       // r: n-index, col: k-base
    bf16x8_t v;
#pragma unroll
    for (int j = 0; j < 8; ++j) v[j] = (bf16_t)tile[col + j][r];
    *(bf16x8_t*)&out[(size_t)(n0 + r) * K + k0 + col] = v;
  }
}

// ------- GEMM: C[M,N] = A[M,K] @ Bt[N,K]^T + bias(f32) [+relu], bf16 MFMA, f32 acc -------
// m97 structure: 128x128 tile, BK=32, 4 waves, 4x4 mfma_f32_16x16x32_bf16, async 16B staging.
template <bool F32OUT>
__global__ __launch_bounds__(256, 2) void gemm_bt_kernel(
    const bf16_t* __restrict__ A, const bf16_t* __restrict__ Bt,
    const float* __restrict__ bias, void* __restrict__ Cv,
    int M, int N, int K, int relu) {
  __shared__ __align__(16) bf16_t lA[128 * 32];
  __shared__ __align__(16) bf16_t lB[128 * 32];
  const int tid = threadIdx.x;
  const int lane = tid & 63;
  const int wave = tid >> 6;
  const int wm64 = (wave & 1) * 64;
  const int wn64 = (wave >> 1) * 64;
  const int row16 = lane & 15;
  const int quad = lane >> 4;
  const size_t m0 = (size_t)blockIdx.y * 128;
  const size_t n0 = (size_t)blockIdx.x * 128;

  f32x4_t acc[4][4];
#pragma unroll
  for (int i = 0; i < 4; ++i)
#pragma unroll
    for (int j = 0; j < 4; ++j)
#pragma unroll
      for (int r = 0; r < 4; ++r) acc[i][j][r] = 0.f;

  const bf16_t* Abase = A + m0 * K;
  const bf16_t* Bbase = Bt + n0 * K;
  // chunk c (0..511): row = c>>2, kcol = (c&3)*8 ; thread owns c = tid, tid+256
  const int r0 = tid >> 2;
  const int r1 = (tid + 256) >> 2;
  const int kc = (tid & 3) * 8;

  for (int kt = 0; kt < K; kt += 32) {
    async16(&lA[tid * 8], Abase + (size_t)r0 * K + kt + kc);
    async16(&lA[(tid + 256) * 8], Abase + (size_t)r1 * K + kt + kc);
    async16(&lB[tid * 8], Bbase + (size_t)r0 * K + kt + kc);
    async16(&lB[(tid + 256) * 8], Bbase + (size_t)r1 * K + kt + kc);
    __syncthreads();
    bf16x8_t af[4], bfr[4];
#pragma unroll
    for (int i = 0; i < 4; ++i)
      af[i] = *(const bf16x8_t*)&lA[(wm64 + i * 16 + row16) * 32 + quad * 8];
#pragma unroll
    for (int i = 0; i < 4; ++i)
      bfr[i] = *(const bf16x8_t*)&lB[(wn64 + i * 16 + row16) * 32 + quad * 8];
#pragma unroll
    for (int i = 0; i < 4; ++i)
#pragma unroll
      for (int j = 0; j < 4; ++j)
        acc[i][j] = __builtin_amdgcn_mfma_f32_16x16x32_bf16(af[i], bfr[j], acc[i][j], 0, 0, 0);
    __syncthreads();
  }

  // C/D layout: col = lane&15, row = quad*4 + reg  [verified m89/m91]
#pragma unroll
  for (int i = 0; i < 4; ++i) {
    size_t row = m0 + wm64 + i * 16 + quad * 4;
#pragma unroll
    for (int j = 0; j < 4; ++j) {
      int col = (int)n0 + wn64 + j * 16 + row16;
      float b = bias[col];
#pragma unroll
      for (int r = 0; r < 4; ++r) {
        float o = acc[i][j][r] + b;
        if (relu) o = fmaxf(o, 0.f);
        if (F32OUT)
          ((float*)Cv)[(row + r) * (size_t)N + col] = o;
        else
          ((bf16_t*)Cv)[(row + r) * (size_t)N + col] = (bf16_t)o;
      }
    }
  }
}

// ---------------- z = mean + var*eps (f32) ----------------
__global__ __launch_bounds__(256) void reparam_kernel(const float* __restrict__ mean,
                                                      const float* __restrict__ var,
                                                      const float* __restrict__ eps,
                                                      float* __restrict__ z) {
  int i = blockIdx.x * 256 + threadIdx.x;  // float4 chunk over NN*LL/4
  f32x4_t m = ((const f32x4_t*)mean)[i];
  f32x4_t v = ((const f32x4_t*)var)[i];
  f32x4_t e = ((const f32x4_t*)eps)[i];
  f32x4_t o;
#pragma unroll
  for (int j = 0; j < 4; ++j) o[j] = m[j] + v[j] * e[j];
  ((f32x4_t*)z)[i] = o;
}

extern "C" void kernel_launch(void* const* d_in, const int* in_sizes, int n_in,
                              void* d_out, int out_size, void* d_ws, size_t ws_size,
                              hipStream_t stream) {
  (void)in_sizes; (void)n_in; (void)out_size; (void)ws_size;
  const float* x0 = (const float*)d_in[0];
  const int* ei = (const int*)d_in[1];
  const int* src = ei;
  const int* dst = ei + EE;
  const float* w1[4] = {(const float*)d_in[2], (const float*)d_in[6],
                        (const float*)d_in[10], (const float*)d_in[14]};
  const float* b1[4] = {(const float*)d_in[3], (const float*)d_in[7],
                        (const float*)d_in[11], (const float*)d_in[15]};
  const float* w2[4] = {(const float*)d_in[4], (const float*)d_in[8],
                        (const float*)d_in[12], (const float*)d_in[16]};
  const float* b2[4] = {(const float*)d_in[5], (const float*)d_in[9],
                        (const float*)d_in[13], (const float*)d_in[17]};
  const float* wm = (const float*)d_in[18];
  const float* bm = (const float*)d_in[19];
  const float* wv = (const float*)d_in[20];
  const float* bv = (const float*)d_in[21];
  const float* eps = (const float*)d_in[22];
  float* out = (float*)d_out;

  // ws layout (bytes): B0 32M | B1 32M | WT(bf16) 8M | deg 32K | cur 32K | rs | csr 1M  (~73.2 MB)
  char* ws = (char*)d_ws;
  bf16_t* B0 = (bf16_t*)(ws);
  bf16_t* B1 = (bf16_t*)(ws + 33554432);
  bf16_t* WT = (bf16_t*)(ws + 67108864);
  int* deg = (int*)(ws + 75497472);
  int* cur = deg + 8192;
  int* rs = deg + 16384;       // 8193 ints (+pad)
  int* csr = deg + 16384 + 8200;

  hipMemsetAsync(deg, 0, 2 * 8192 * sizeof(int), stream);
  count_deg_kernel<<<EE / 256, 256, 0, stream>>>(dst, deg);
  scan_kernel<<<1, 1024, 0, stream>>>(deg, rs);
  fill_csr_kernel<<<EE / 256, 256, 0, stream>>>(src, dst, rs, cur, csr);

  auto T = [&](const float* w, int K, int Nn) {
    transpose_cast_kernel<<<dim3(Nn / 64, K / 64), 256, 0, stream>>>(w, WT, K, Nn);
  };
  auto G = [&](const bf16_t* A, const float* bias, bf16_t* C, int M, int Nn, int K, int relu) {
    gemm_bt_kernel<false><<<dim3(Nn / 128, M / 128), 256, 0, stream>>>(A, WT, bias, (void*)C, M, Nn, K, relu);
  };
  auto GF = [&](const bf16_t* A, const float* bias, float* C, int M, int Nn, int K) {
    gemm_bt_kernel<true><<<dim3(Nn / 128, M / 128), 256, 0, stream>>>(A, WT, bias, (void*)C, M, Nn, K, 0);
  };

  // Layer 0: x0 f32 [N,256] -> bf16 (B0) -> agg (B1) -> h (B0) -> x1 (B1)
  cast_kernel<<<(NN * TT / 8) / 256, 256, 0, stream>>>(x0, B0);
  agg0_kernel<<<NN / 2, 64, 0, stream>>>(B0, B1, rs, csr);
  T(w1[0], TT, HH); G(B1, b1[0], B0, NN, HH, TT, 1);
  T(w2[0], HH, HH); G(B0, b2[0], B1, NN, HH, HH, 1);
  // Layer 1: x1 (B1) -> x2 (B0)
  agg_bf16_kernel<<<NN, 256, 0, stream>>>(B1, B0, rs, csr);
  T(w1[1], HH, HH); G(B0, b1[1], B1, NN, HH, HH, 1);
  T(w2[1], HH, HH); G(B1, b2[1], B0, NN, HH, HH, 1);
  // Layer 2: x2 (B0) -> x3 (B1)
  agg_bf16_kernel<<<NN, 256, 0, stream>>>(B0, B1, rs, csr);
  T(w1[2], HH, HH); G(B1, b1[2], B0, NN, HH, HH, 1);
  T(w2[2], HH, HH); G(B0, b2[2], B1, NN, HH, HH, 1);
  // Layer 3: x3 (B1) -> x4 (B0) [N,1024], no relu after last conv
  agg_bf16_kernel<<<NN, 256, 0, stream>>>(B1, B0, rs, csr);
  T(w1[3], HH, OO); G(B0, b1[3], B1, NN, OO, HH, 1);
  T(w2[3], OO, OO); G(B1, b2[3], B0, NN, OO, OO, 0);
  // Heads (f32 out): mean -> out[NL:2NL], var -> out[2NL:3NL]
  T(wm, OO, LL); GF(B0, bm, out + (size_t)NN * LL, NN, LL, OO);
  T(wv, OO, LL); GF(B0, bv, out + (size_t)2 * NN * LL, NN, LL, OO);
  // z = mean + var*eps -> out[0:NL]
  reparam_kernel<<<(NN * LL / 4) / 256, 256, 0, stream>>>(
      out + (size_t)NN * LL, out + (size_t)2 * NN * LL, eps, out);
}

// Round 5
// 1053.496 us; speedup vs baseline: 1.2868x; 1.1537x over previous
//
#include <hip/hip_runtime.h>

#define NN 8192
#define EE 262144
#define TT 256
#define HH 2048
#define OO 1024
#define LL 128

typedef __bf16 bf16_t;
typedef __bf16 bf16x8_t __attribute__((ext_vector_type(8)));
typedef float f32x4_t __attribute__((ext_vector_type(4)));

__device__ __forceinline__ void async16(void* lds, const void* g) {
  __builtin_amdgcn_global_load_lds(
      (const __attribute__((address_space(1))) void*)g,
      (__attribute__((address_space(3))) void*)lds, 16, 0, 0);
}

// ---------------- CSR build (dst-major) ----------------
__global__ __launch_bounds__(256) void count_deg_kernel(const int* __restrict__ dst,
                                                        int* __restrict__ deg) {
  int e = blockIdx.x * 256 + threadIdx.x;
  if (e < EE) atomicAdd(&deg[dst[e]], 1);
}

__global__ __launch_bounds__(1024) void scan_kernel(const int* __restrict__ deg,
                                                    int* __restrict__ rs) {
  __shared__ int s[1024];
  int t = threadIdx.x;
  int pre[8];
  int sum = 0;
#pragma unroll
  for (int j = 0; j < 8; ++j) { pre[j] = sum; sum += deg[t * 8 + j]; }
  s[t] = sum;
  __syncthreads();
  for (int off = 1; off < 1024; off <<= 1) {
    int add = (t >= off) ? s[t - off] : 0;
    __syncthreads();
    s[t] += add;
    __syncthreads();
  }
  int base = (t == 0) ? 0 : s[t - 1];
#pragma unroll
  for (int j = 0; j < 8; ++j) rs[t * 8 + j] = base + pre[j];
  if (t == 1023) rs[8192] = s[1023];
}

__global__ __launch_bounds__(256) void fill_csr_kernel(const int* __restrict__ src,
                                                       const int* __restrict__ dst,
                                                       const int* __restrict__ rs,
                                                       int* __restrict__ cur,
                                                       int* __restrict__ csr) {
  int e = blockIdx.x * 256 + threadIdx.x;
  if (e >= EE) return;
  int d = dst[e];
  int p = atomicAdd(&cur[d], 1);
  csr[rs[d] + p] = src[e];
}

// ---------------- cast f32 -> bf16 (vectorized) ----------------
__global__ __launch_bounds__(256) void cast_kernel(const float* __restrict__ in,
                                                   bf16_t* __restrict__ out) {
  int i = blockIdx.x * 256 + threadIdx.x;  // bf16x8 chunk over NN*TT/8
  f32x4_t a = ((const f32x4_t*)in)[i * 2];
  f32x4_t b = ((const f32x4_t*)in)[i * 2 + 1];
  bf16x8_t o;
#pragma unroll
  for (int j = 0; j < 4; ++j) { o[j] = (bf16_t)a[j]; o[4 + j] = (bf16_t)b[j]; }
  ((bf16x8_t*)out)[i] = o;
}

// ------- layer-0 aggregation, d=256 (32 chunks): 2 nodes per 64-thread block -------
// 4 MB working set fits any single XCD L2 — no tiling needed.
__global__ __launch_bounds__(64) void agg0_kernel(const bf16_t* __restrict__ x,
                                                  bf16_t* __restrict__ out,
                                                  const int* __restrict__ rs,
                                                  const int* __restrict__ csr) {
  int t = threadIdx.x;
  int node = blockIdx.x * 2 + (t >> 5);
  int c = t & 31;
  const bf16x8_t* xv = (const bf16x8_t*)x;
  bf16x8_t self = xv[(size_t)node * 32 + c];
  float acc[8];
#pragma unroll
  for (int j = 0; j < 8; ++j) acc[j] = (float)self[j];
  int e0 = rs[node], e1 = rs[node + 1];
  int e = e0;
  for (; e + 4 <= e1; e += 4) {
    int s0 = csr[e], s1 = csr[e + 1], s2 = csr[e + 2], s3 = csr[e + 3];
    bf16x8_t v0 = xv[(size_t)s0 * 32 + c];
    bf16x8_t v1 = xv[(size_t)s1 * 32 + c];
    bf16x8_t v2 = xv[(size_t)s2 * 32 + c];
    bf16x8_t v3 = xv[(size_t)s3 * 32 + c];
#pragma unroll
    for (int j = 0; j < 8; ++j)
      acc[j] += (float)v0[j] + (float)v1[j] + (float)v2[j] + (float)v3[j];
  }
  for (; e < e1; ++e) {
    bf16x8_t v = xv[(size_t)csr[e] * 32 + c];
#pragma unroll
    for (int j = 0; j < 8; ++j) acc[j] += (float)v[j];
  }
  bf16x8_t o;
#pragma unroll
  for (int j = 0; j < 8; ++j) o[j] = (bf16_t)acc[j];
  ((bf16x8_t*)out)[(size_t)node * 32 + c] = o;
}

// ------- aggregation d=2048, col-tiled for XCD-L2 residency -------
// Tile = 256 cols (512 B/row -> 4 MB working set per tile = one XCD L2).
// Grid (1024 node-groups, 8 tiles), x-fastest so one tile floods all XCDs at a time.
// Block = 256 threads = 8 nodes x 32 chunks (16 B/lane, 256 B/row-segment coalesced).
__global__ __launch_bounds__(256) void agg_tiled_kernel(const bf16_t* __restrict__ x,
                                                        bf16_t* __restrict__ out,
                                                        const int* __restrict__ rs,
                                                        const int* __restrict__ csr) {
  int t = threadIdx.x;
  int node = blockIdx.x * 8 + (t >> 5);
  int cb = blockIdx.y * 32 + (t & 31);   // global chunk index (0..255)
  const bf16x8_t* xv = (const bf16x8_t*)x;
  bf16x8_t self = xv[(size_t)node * 256 + cb];
  float acc[8];
#pragma unroll
  for (int j = 0; j < 8; ++j) acc[j] = (float)self[j];
  int e0 = rs[node], e1 = rs[node + 1];
  int e = e0;
  for (; e + 4 <= e1; e += 4) {
    int s0 = csr[e], s1 = csr[e + 1], s2 = csr[e + 2], s3 = csr[e + 3];
    bf16x8_t v0 = xv[(size_t)s0 * 256 + cb];
    bf16x8_t v1 = xv[(size_t)s1 * 256 + cb];
    bf16x8_t v2 = xv[(size_t)s2 * 256 + cb];
    bf16x8_t v3 = xv[(size_t)s3 * 256 + cb];
#pragma unroll
    for (int j = 0; j < 8; ++j)
      acc[j] += (float)v0[j] + (float)v1[j] + (float)v2[j] + (float)v3[j];
  }
  for (; e < e1; ++e) {
    bf16x8_t v = xv[(size_t)csr[e] * 256 + cb];
#pragma unroll
    for (int j = 0; j < 8; ++j) acc[j] += (float)v[j];
  }
  bf16x8_t o;
#pragma unroll
  for (int j = 0; j < 8; ++j) o[j] = (bf16_t)acc[j];
  ((bf16x8_t*)out)[(size_t)node * 256 + cb] = o;
}

// ---------------- transpose + cast: f32 [K,N] -> bf16 [N,K] ----------------
__global__ __launch_bounds__(256) void transpose_cast_kernel(const float* __restrict__ in,
                                                             bf16_t* __restrict__ out,
                                                             int K, int N) {
  __shared__ float tile[64][65];
  int n0 = blockIdx.x * 64, k0 = blockIdx.y * 64;
  int t = threadIdx.x;
  for (int c = t; c < 1024; c += 256) {      // 64 rows x 16 float4 chunks
    int r = c >> 4, col = (c & 15) * 4;
    f32x4_t v = *(const f32x4_t*)&in[(size_t)(k0 + r) * N + n0 + col];
#pragma unroll
    for (int j = 0; j < 4; ++j) tile[r][col + j] = v[j];
  }
  __syncthreads();
  for (int c = t; c < 512; c += 256) {       // 64 n-rows x 8 bf16x8 chunks
    int r = c >> 3, col = (c & 7) * 8;       // r: n-index, col: k-base
    bf16x8_t v;
#pragma unroll
    for (int j = 0; j < 8; ++j) v[j] = (bf16_t)tile[col + j][r];
    *(bf16x8_t*)&out[(size_t)(n0 + r) * K + k0 + col] = v;
  }
}

// ------- GEMM: C[M,N] = A[M,K] @ Bt[N,K]^T + bias(f32) [+relu], bf16 MFMA, f32 acc -------
// m97 structure: 128x128 tile, BK=32, 4 waves, 4x4 mfma_f32_16x16x32_bf16, async 16B staging.
template <bool F32OUT>
__global__ __launch_bounds__(256, 2) void gemm_bt_kernel(
    const bf16_t* __restrict__ A, const bf16_t* __restrict__ Bt,
    const float* __restrict__ bias, void* __restrict__ Cv,
    int M, int N, int K, int relu) {
  __shared__ __align__(16) bf16_t lA[128 * 32];
  __shared__ __align__(16) bf16_t lB[128 * 32];
  const int tid = threadIdx.x;
  const int lane = tid & 63;
  const int wave = tid >> 6;
  const int wm64 = (wave & 1) * 64;
  const int wn64 = (wave >> 1) * 64;
  const int row16 = lane & 15;
  const int quad = lane >> 4;
  const size_t m0 = (size_t)blockIdx.y * 128;
  const size_t n0 = (size_t)blockIdx.x * 128;

  f32x4_t acc[4][4];
#pragma unroll
  for (int i = 0; i < 4; ++i)
#pragma unroll
    for (int j = 0; j < 4; ++j)
#pragma unroll
      for (int r = 0; r < 4; ++r) acc[i][j][r] = 0.f;

  const bf16_t* Abase = A + m0 * K;
  const bf16_t* Bbase = Bt + n0 * K;
  // chunk c (0..511): row = c>>2, kcol = (c&3)*8 ; thread owns c = tid, tid+256
  const int r0 = tid >> 2;
  const int r1 = (tid + 256) >> 2;
  const int kc = (tid & 3) * 8;

  for (int kt = 0; kt < K; kt += 32) {
    async16(&lA[tid * 8], Abase + (size_t)r0 * K + kt + kc);
    async16(&lA[(tid + 256) * 8], Abase + (size_t)r1 * K + kt + kc);
    async16(&lB[tid * 8], Bbase + (size_t)r0 * K + kt + kc);
    async16(&lB[(tid + 256) * 8], Bbase + (size_t)r1 * K + kt + kc);
    __syncthreads();
    bf16x8_t af[4], bfr[4];
#pragma unroll
    for (int i = 0; i < 4; ++i)
      af[i] = *(const bf16x8_t*)&lA[(wm64 + i * 16 + row16) * 32 + quad * 8];
#pragma unroll
    for (int i = 0; i < 4; ++i)
      bfr[i] = *(const bf16x8_t*)&lB[(wn64 + i * 16 + row16) * 32 + quad * 8];
#pragma unroll
    for (int i = 0; i < 4; ++i)
#pragma unroll
      for (int j = 0; j < 4; ++j)
        acc[i][j] = __builtin_amdgcn_mfma_f32_16x16x32_bf16(af[i], bfr[j], acc[i][j], 0, 0, 0);
    __syncthreads();
  }

  // C/D layout: col = lane&15, row = quad*4 + reg  [verified m89/m91]
#pragma unroll
  for (int i = 0; i < 4; ++i) {
    size_t row = m0 + wm64 + i * 16 + quad * 4;
#pragma unroll
    for (int j = 0; j < 4; ++j) {
      int col = (int)n0 + wn64 + j * 16 + row16;
      float b = bias[col];
#pragma unroll
      for (int r = 0; r < 4; ++r) {
        float o = acc[i][j][r] + b;
        if (relu) o = fmaxf(o, 0.f);
        if (F32OUT)
          ((float*)Cv)[(row + r) * (size_t)N + col] = o;
        else
          ((bf16_t*)Cv)[(row + r) * (size_t)N + col] = (bf16_t)o;
      }
    }
  }
}

// ---------------- z = mean + var*eps (f32) ----------------
__global__ __launch_bounds__(256) void reparam_kernel(const float* __restrict__ mean,
                                                      const float* __restrict__ var,
                                                      const float* __restrict__ eps,
                                                      float* __restrict__ z) {
  int i = blockIdx.x * 256 + threadIdx.x;  // float4 chunk over NN*LL/4
  f32x4_t m = ((const f32x4_t*)mean)[i];
  f32x4_t v = ((const f32x4_t*)var)[i];
  f32x4_t e = ((const f32x4_t*)eps)[i];
  f32x4_t o;
#pragma unroll
  for (int j = 0; j < 4; ++j) o[j] = m[j] + v[j] * e[j];
  ((f32x4_t*)z)[i] = o;
}

extern "C" void kernel_launch(void* const* d_in, const int* in_sizes, int n_in,
                              void* d_out, int out_size, void* d_ws, size_t ws_size,
                              hipStream_t stream) {
  (void)in_sizes; (void)n_in; (void)out_size; (void)ws_size;
  const float* x0 = (const float*)d_in[0];
  const int* ei = (const int*)d_in[1];
  const int* src = ei;
  const int* dst = ei + EE;
  const float* w1[4] = {(const float*)d_in[2], (const float*)d_in[6],
                        (const float*)d_in[10], (const float*)d_in[14]};
  const float* b1[4] = {(const float*)d_in[3], (const float*)d_in[7],
                        (const float*)d_in[11], (const float*)d_in[15]};
  const float* w2[4] = {(const float*)d_in[4], (const float*)d_in[8],
                        (const float*)d_in[12], (const float*)d_in[16]};
  const float* b2[4] = {(const float*)d_in[5], (const float*)d_in[9],
                        (const float*)d_in[13], (const float*)d_in[17]};
  const float* wm = (const float*)d_in[18];
  const float* bm = (const float*)d_in[19];
  const float* wv = (const float*)d_in[20];
  const float* bv = (const float*)d_in[21];
  const float* eps = (const float*)d_in[22];
  float* out = (float*)d_out;

  // ws layout (bytes): B0 32M | B1 32M | WT(bf16) 8M | deg 32K | cur 32K | rs | csr 1M  (~73.2 MB)
  char* ws = (char*)d_ws;
  bf16_t* B0 = (bf16_t*)(ws);
  bf16_t* B1 = (bf16_t*)(ws + 33554432);
  bf16_t* WT = (bf16_t*)(ws + 67108864);
  int* deg = (int*)(ws + 75497472);
  int* cur = deg + 8192;
  int* rs = deg + 16384;       // 8193 ints (+pad)
  int* csr = deg + 16384 + 8200;

  hipMemsetAsync(deg, 0, 2 * 8192 * sizeof(int), stream);
  count_deg_kernel<<<EE / 256, 256, 0, stream>>>(dst, deg);
  scan_kernel<<<1, 1024, 0, stream>>>(deg, rs);
  fill_csr_kernel<<<EE / 256, 256, 0, stream>>>(src, dst, rs, cur, csr);

  auto T = [&](const float* w, int K, int Nn) {
    transpose_cast_kernel<<<dim3(Nn / 64, K / 64), 256, 0, stream>>>(w, WT, K, Nn);
  };
  auto G = [&](const bf16_t* A, const float* bias, bf16_t* C, int M, int Nn, int K, int relu) {
    gemm_bt_kernel<false><<<dim3(Nn / 128, M / 128), 256, 0, stream>>>(A, WT, bias, (void*)C, M, Nn, K, relu);
  };
  auto GF = [&](const bf16_t* A, const float* bias, float* C, int M, int Nn, int K) {
    gemm_bt_kernel<true><<<dim3(Nn / 128, M / 128), 256, 0, stream>>>(A, WT, bias, (void*)C, M, Nn, K, 0);
  };
  auto AGG = [&](const bf16_t* in, bf16_t* outp) {
    agg_tiled_kernel<<<dim3(NN / 8, 8), 256, 0, stream>>>(in, outp, rs, csr);
  };

  // Layer 0: x0 f32 [N,256] -> bf16 (B0) -> agg (B1) -> h (B0) -> x1 (B1)
  cast_kernel<<<(NN * TT / 8) / 256, 256, 0, stream>>>(x0, B0);
  agg0_kernel<<<NN / 2, 64, 0, stream>>>(B0, B1, rs, csr);
  T(w1[0], TT, HH); G(B1, b1[0], B0, NN, HH, TT, 1);
  T(w2[0], HH, HH); G(B0, b2[0], B1, NN, HH, HH, 1);
  // Layer 1: x1 (B1) -> x2 (B0)
  AGG(B1, B0);
  T(w1[1], HH, HH); G(B0, b1[1], B1, NN, HH, HH, 1);
  T(w2[1], HH, HH); G(B1, b2[1], B0, NN, HH, HH, 1);
  // Layer 2: x2 (B0) -> x3 (B1)
  AGG(B0, B1);
  T(w1[2], HH, HH); G(B1, b1[2], B0, NN, HH, HH, 1);
  T(w2[2], HH, HH); G(B0, b2[2], B1, NN, HH, HH, 1);
  // Layer 3: x3 (B1) -> x4 (B0) [N,1024], no relu after last conv
  AGG(B1, B0);
  T(w1[3], HH, OO); G(B0, b1[3], B1, NN, OO, HH, 1);
  T(w2[3], OO, OO); G(B1, b2[3], B0, NN, OO, OO, 0);
  // Heads (f32 out): mean -> out[NL:2NL], var -> out[2NL:3NL]
  T(wm, OO, LL); GF(B0, bm, out + (size_t)NN * LL, NN, LL, OO);
  T(wv, OO, LL); GF(B0, bv, out + (size_t)2 * NN * LL, NN, LL, OO);
  // z = mean + var*eps -> out[0:NL]
  reparam_kernel<<<(NN * LL / 4) / 256, 256, 0, stream>>>(
      out + (size_t)NN * LL, out + (size_t)2 * NN * LL, eps, out);
}

// Round 6
// 1013.547 us; speedup vs baseline: 1.3376x; 1.0394x over previous
//
#include <hip/hip_runtime.h>

#define NN 8192
#define EE 262144
#define TT 256
#define HH 2048
#define OO 1024
#define LL 128

typedef __bf16 bf16_t;
typedef __bf16 bf16x8_t __attribute__((ext_vector_type(8)));
typedef float f32x4_t __attribute__((ext_vector_type(4)));

__device__ __forceinline__ void async16(void* lds, const void* g) {
  __builtin_amdgcn_global_load_lds(
      (const __attribute__((address_space(1))) void*)g,
      (__attribute__((address_space(3))) void*)lds, 16, 0, 0);
}

// Activations live in 256-col tiled layout:
//   elem(row, col) at  (col>>8)*NN*256 + row*256 + (col&255)
// so each 256-col tile is a dense 4 MB block (= one XCD L2).

// ---------------- CSR build (dst-major) ----------------
__global__ __launch_bounds__(256) void count_deg_kernel(const int* __restrict__ dst,
                                                        int* __restrict__ deg) {
  int e = blockIdx.x * 256 + threadIdx.x;
  if (e < EE) atomicAdd(&deg[dst[e]], 1);
}

__global__ __launch_bounds__(1024) void scan_kernel(const int* __restrict__ deg,
                                                    int* __restrict__ rs) {
  __shared__ int s[1024];
  int t = threadIdx.x;
  int pre[8];
  int sum = 0;
#pragma unroll
  for (int j = 0; j < 8; ++j) { pre[j] = sum; sum += deg[t * 8 + j]; }
  s[t] = sum;
  __syncthreads();
  for (int off = 1; off < 1024; off <<= 1) {
    int add = (t >= off) ? s[t - off] : 0;
    __syncthreads();
    s[t] += add;
    __syncthreads();
  }
  int base = (t == 0) ? 0 : s[t - 1];
#pragma unroll
  for (int j = 0; j < 8; ++j) rs[t * 8 + j] = base + pre[j];
  if (t == 1023) rs[8192] = s[1023];
}

__global__ __launch_bounds__(256) void fill_csr_kernel(const int* __restrict__ src,
                                                       const int* __restrict__ dst,
                                                       const int* __restrict__ rs,
                                                       int* __restrict__ cur,
                                                       int* __restrict__ csr) {
  int e = blockIdx.x * 256 + threadIdx.x;
  if (e >= EE) return;
  int d = dst[e];
  int p = atomicAdd(&cur[d], 1);
  csr[rs[d] + p] = src[e];
}

// ---------------- cast f32 -> bf16 (d=256: tiled == linear) ----------------
__global__ __launch_bounds__(256) void cast_kernel(const float* __restrict__ in,
                                                   bf16_t* __restrict__ out) {
  int i = blockIdx.x * 256 + threadIdx.x;
  f32x4_t a = ((const f32x4_t*)in)[i * 2];
  f32x4_t b = ((const f32x4_t*)in)[i * 2 + 1];
  bf16x8_t o;
#pragma unroll
  for (int j = 0; j < 4; ++j) { o[j] = (bf16_t)a[j]; o[4 + j] = (bf16_t)b[j]; }
  ((bf16x8_t*)out)[i] = o;
}

// ------- layer-0 aggregation, d=256 (single tile, linear layout) -------
__global__ __launch_bounds__(64) void agg0_kernel(const bf16_t* __restrict__ x,
                                                  bf16_t* __restrict__ out,
                                                  const int* __restrict__ rs,
                                                  const int* __restrict__ csr) {
  int t = threadIdx.x;
  int node = blockIdx.x * 2 + (t >> 5);
  int c = t & 31;
  const bf16x8_t* xv = (const bf16x8_t*)x;
  bf16x8_t self = xv[(size_t)node * 32 + c];
  float acc[8];
#pragma unroll
  for (int j = 0; j < 8; ++j) acc[j] = (float)self[j];
  int e0 = rs[node], e1 = rs[node + 1];
  int e = e0;
  for (; e + 4 <= e1; e += 4) {
    int s0 = csr[e], s1 = csr[e + 1], s2 = csr[e + 2], s3 = csr[e + 3];
    bf16x8_t v0 = xv[(size_t)s0 * 32 + c];
    bf16x8_t v1 = xv[(size_t)s1 * 32 + c];
    bf16x8_t v2 = xv[(size_t)s2 * 32 + c];
    bf16x8_t v3 = xv[(size_t)s3 * 32 + c];
#pragma unroll
    for (int j = 0; j < 8; ++j)
      acc[j] += (float)v0[j] + (float)v1[j] + (float)v2[j] + (float)v3[j];
  }
  for (; e < e1; ++e) {
    bf16x8_t v = xv[(size_t)csr[e] * 32 + c];
#pragma unroll
    for (int j = 0; j < 8; ++j) acc[j] += (float)v[j];
  }
  bf16x8_t o;
#pragma unroll
  for (int j = 0; j < 8; ++j) o[j] = (bf16_t)acc[j];
  ((bf16x8_t*)out)[(size_t)node * 32 + c] = o;
}

// ------- aggregation over tiled activations; optional fused bias+relu -------
// Grid (NN/8, d/256); block 256 = 8 nodes x 32 chunks. Tile = dense 4 MB block.
__global__ __launch_bounds__(256) void agg_tiled_kernel(const bf16_t* __restrict__ x,
                                                        bf16_t* __restrict__ out,
                                                        const int* __restrict__ rs,
                                                        const int* __restrict__ csr,
                                                        const float* __restrict__ bias,
                                                        int relu) {
  int t = threadIdx.x;
  int node = blockIdx.x * 8 + (t >> 5);
  int c = t & 31;
  size_t tb = (size_t)blockIdx.y * (NN * 32);   // tile base, in bf16x8 units
  const bf16x8_t* xv = (const bf16x8_t*)x + tb;
  bf16x8_t self = xv[node * 32 + c];
  float acc[8];
#pragma unroll
  for (int j = 0; j < 8; ++j) acc[j] = (float)self[j];
  int e0 = rs[node], e1 = rs[node + 1];
  int e = e0;
  for (; e + 4 <= e1; e += 4) {
    int s0 = csr[e], s1 = csr[e + 1], s2 = csr[e + 2], s3 = csr[e + 3];
    bf16x8_t v0 = xv[s0 * 32 + c];
    bf16x8_t v1 = xv[s1 * 32 + c];
    bf16x8_t v2 = xv[s2 * 32 + c];
    bf16x8_t v3 = xv[s3 * 32 + c];
#pragma unroll
    for (int j = 0; j < 8; ++j)
      acc[j] += (float)v0[j] + (float)v1[j] + (float)v2[j] + (float)v3[j];
  }
  for (; e < e1; ++e) {
    bf16x8_t v = xv[csr[e] * 32 + c];
#pragma unroll
    for (int j = 0; j < 8; ++j) acc[j] += (float)v[j];
  }
  if (bias) {
    const float* bp = bias + blockIdx.y * 256 + c * 8;
    f32x4_t b0 = *(const f32x4_t*)bp;
    f32x4_t b1 = *(const f32x4_t*)(bp + 4);
#pragma unroll
    for (int j = 0; j < 4; ++j) { acc[j] += b0[j]; acc[4 + j] += b1[j]; }
  }
  if (relu) {
#pragma unroll
    for (int j = 0; j < 8; ++j) acc[j] = fmaxf(acc[j], 0.f);
  }
  bf16x8_t o;
#pragma unroll
  for (int j = 0; j < 8; ++j) o[j] = (bf16_t)acc[j];
  ((bf16x8_t*)out + tb)[node * 32 + c] = o;
}

// ---------------- transpose + cast: f32 [K,N] -> bf16 [N,K] ----------------
__global__ __launch_bounds__(256) void transpose_cast_kernel(const float* __restrict__ in,
                                                             bf16_t* __restrict__ out,
                                                             int K, int N) {
  __shared__ float tile[64][65];
  int n0 = blockIdx.x * 64, k0 = blockIdx.y * 64;
  int t = threadIdx.x;
  for (int c = t; c < 1024; c += 256) {
    int r = c >> 4, col = (c & 15) * 4;
    f32x4_t v = *(const f32x4_t*)&in[(size_t)(k0 + r) * N + n0 + col];
#pragma unroll
    for (int j = 0; j < 4; ++j) tile[r][col + j] = v[j];
  }
  __syncthreads();
  for (int c = t; c < 512; c += 256) {
    int r = c >> 3, col = (c & 7) * 8;
    bf16x8_t v;
#pragma unroll
    for (int j = 0; j < 8; ++j) v[j] = (bf16_t)tile[col + j][r];
    *(bf16x8_t*)&out[(size_t)(n0 + r) * K + k0 + col] = v;
  }
}

// ------- GEMM: C = A(tiled) @ Bt^T + bias [+relu]; M == NN fixed -------
// CMODE 0: bf16 tiled output. CMODE 1: head f32 split output (col<128 -> mean, else var).
template <int CMODE>
__global__ __launch_bounds__(256, 2) void gemm_bt_kernel(
    const bf16_t* __restrict__ A, const bf16_t* __restrict__ Bt,
    const float* __restrict__ bias, void* __restrict__ Cv,
    int N, int K, int relu) {
  __shared__ __align__(16) bf16_t lA[128 * 32];
  __shared__ __align__(16) bf16_t lB[128 * 32];
  const int tid = threadIdx.x;
  const int lane = tid & 63;
  const int wave = tid >> 6;
  const int wm64 = (wave & 1) * 64;
  const int wn64 = (wave >> 1) * 64;
  const int row16 = lane & 15;
  const int quad = lane >> 4;
  const size_t m0 = (size_t)blockIdx.y * 128;
  const size_t n0 = (size_t)blockIdx.x * 128;

  f32x4_t acc[4][4];
#pragma unroll
  for (int i = 0; i < 4; ++i)
#pragma unroll
    for (int j = 0; j < 4; ++j)
#pragma unroll
      for (int r = 0; r < 4; ++r) acc[i][j][r] = 0.f;

  const bf16_t* Bbase = Bt + n0 * K;
  const int r0 = tid >> 2;
  const int r1 = (tid + 256) >> 2;
  const int kc = (tid & 3) * 8;

  for (int kt = 0; kt < K; kt += 32) {
    // tiled A: (k>>8)*NN*256 + row*256 + (k&255)
    const bf16_t* Ab = A + ((size_t)(kt >> 8)) * (NN * 256) + (kt & 255) + kc;
    async16(&lA[tid * 8], Ab + (m0 + r0) * 256);
    async16(&lA[(tid + 256) * 8], Ab + (m0 + r1) * 256);
    async16(&lB[tid * 8], Bbase + (size_t)r0 * K + kt + kc);
    async16(&lB[(tid + 256) * 8], Bbase + (size_t)r1 * K + kt + kc);
    __syncthreads();
    bf16x8_t af[4], bfr[4];
#pragma unroll
    for (int i = 0; i < 4; ++i)
      af[i] = *(const bf16x8_t*)&lA[(wm64 + i * 16 + row16) * 32 + quad * 8];
#pragma unroll
    for (int i = 0; i < 4; ++i)
      bfr[i] = *(const bf16x8_t*)&lB[(wn64 + i * 16 + row16) * 32 + quad * 8];
#pragma unroll
    for (int i = 0; i < 4; ++i)
#pragma unroll
      for (int j = 0; j < 4; ++j)
        acc[i][j] = __builtin_amdgcn_mfma_f32_16x16x32_bf16(af[i], bfr[j], acc[i][j], 0, 0, 0);
    __syncthreads();
  }

  // C/D layout: col = lane&15, row = quad*4 + reg  [verified m89/m91]
#pragma unroll
  for (int i = 0; i < 4; ++i) {
    size_t row = m0 + wm64 + i * 16 + quad * 4;
#pragma unroll
    for (int j = 0; j < 4; ++j) {
      int col = (int)n0 + wn64 + j * 16 + row16;
      float b = bias ? bias[col] : 0.f;
      if (CMODE == 0) {
        size_t cb = ((size_t)(col >> 8)) * (NN * 256) + (col & 255);
#pragma unroll
        for (int r = 0; r < 4; ++r) {
          float o = acc[i][j][r] + b;
          if (relu) o = fmaxf(o, 0.f);
          ((bf16_t*)Cv)[cb + (row + r) * 256] = (bf16_t)o;
        }
      } else {
        int sel = col >> 7;          // 0 -> mean, 1 -> var
        int c2 = col & 127;
        float* dst = (float*)Cv + (size_t)(1 + sel) * NN * LL + c2;
#pragma unroll
        for (int r = 0; r < 4; ++r) {
          dst[(row + r) * LL] = acc[i][j][r] + b;
        }
      }
    }
  }
}

// ---------------- z = mean + var*eps (f32) ----------------
__global__ __launch_bounds__(256) void reparam_kernel(const float* __restrict__ mean,
                                                      const float* __restrict__ var,
                                                      const float* __restrict__ eps,
                                                      float* __restrict__ z) {
  int i = blockIdx.x * 256 + threadIdx.x;
  f32x4_t m = ((const f32x4_t*)mean)[i];
  f32x4_t v = ((const f32x4_t*)var)[i];
  f32x4_t e = ((const f32x4_t*)eps)[i];
  f32x4_t o;
#pragma unroll
  for (int j = 0; j < 4; ++j) o[j] = m[j] + v[j] * e[j];
  ((f32x4_t*)z)[i] = o;
}

extern "C" void kernel_launch(void* const* d_in, const int* in_sizes, int n_in,
                              void* d_out, int out_size, void* d_ws, size_t ws_size,
                              hipStream_t stream) {
  (void)in_sizes; (void)n_in; (void)out_size; (void)ws_size;
  const float* x0 = (const float*)d_in[0];
  const int* ei = (const int*)d_in[1];
  const int* src = ei;
  const int* dst = ei + EE;
  const float* w1[4] = {(const float*)d_in[2], (const float*)d_in[6],
                        (const float*)d_in[10], (const float*)d_in[14]};
  const float* b1[4] = {(const float*)d_in[3], (const float*)d_in[7],
                        (const float*)d_in[11], (const float*)d_in[15]};
  const float* w2[4] = {(const float*)d_in[4], (const float*)d_in[8],
                        (const float*)d_in[12], (const float*)d_in[16]};
  const float* b2[4] = {(const float*)d_in[5], (const float*)d_in[9],
                        (const float*)d_in[13], (const float*)d_in[17]};
  const float* wm = (const float*)d_in[18];
  const float* bm = (const float*)d_in[19];
  const float* wv = (const float*)d_in[20];
  const float* bv = (const float*)d_in[21];
  const float* eps = (const float*)d_in[22];
  float* out = (float*)d_out;

  // ws: B0 32M | B1 32M | WT(bf16) 8M | deg/cur/rs/csr | headbias
  char* ws = (char*)d_ws;
  bf16_t* B0 = (bf16_t*)(ws);
  bf16_t* B1 = (bf16_t*)(ws + 33554432);
  bf16_t* WT = (bf16_t*)(ws + 67108864);
  int* deg = (int*)(ws + 75497472);
  int* cur = deg + 8192;
  int* rs = deg + 16384;
  int* csr = deg + 16384 + 8200;
  float* hb = (float*)(csr + 262144);   // 256 floats

  hipMemsetAsync(deg, 0, 2 * 8192 * sizeof(int), stream);
  count_deg_kernel<<<EE / 256, 256, 0, stream>>>(dst, deg);
  scan_kernel<<<1, 1024, 0, stream>>>(deg, rs);
  fill_csr_kernel<<<EE / 256, 256, 0, stream>>>(src, dst, rs, cur, csr);
  hipMemcpyAsync(hb, bm, 128 * sizeof(float), hipMemcpyDeviceToDevice, stream);
  hipMemcpyAsync(hb + 128, bv, 128 * sizeof(float), hipMemcpyDeviceToDevice, stream);

  auto T = [&](const float* w, int K, int Nn, bf16_t* dstw) {
    transpose_cast_kernel<<<dim3(Nn / 64, K / 64), 256, 0, stream>>>(w, dstw, K, Nn);
  };
  auto G = [&](const bf16_t* A, const float* bias, bf16_t* C, int Nn, int K, int relu) {
    gemm_bt_kernel<0><<<dim3(Nn / 128, NN / 128), 256, 0, stream>>>(A, WT, bias, (void*)C, Nn, K, relu);
  };
  auto AGG = [&](const bf16_t* in, bf16_t* outp, int d, const float* bias, int relu) {
    agg_tiled_kernel<<<dim3(NN / 8, d / 256), 256, 0, stream>>>(in, outp, rs, csr, bias, relu);
  };

  // Layer 0: x0 f32 [N,256] -> bf16 (B0) -> agg (B1) -> h (B0) -> x1 (B1)
  cast_kernel<<<(NN * TT / 8) / 256, 256, 0, stream>>>(x0, B0);
  agg0_kernel<<<NN / 2, 64, 0, stream>>>(B0, B1, rs, csr);
  T(w1[0], TT, HH, WT); G(B1, b1[0], B0, HH, TT, 1);
  T(w2[0], HH, HH, WT); G(B0, b2[0], B1, HH, HH, 1);
  // Layer 1: x1 (B1) -> x2 (B0)
  AGG(B1, B0, HH, nullptr, 0);
  T(w1[1], HH, HH, WT); G(B0, b1[1], B1, HH, HH, 1);
  T(w2[1], HH, HH, WT); G(B1, b2[1], B0, HH, HH, 1);
  // Layer 2: x2 (B0) -> x3 (B1)
  AGG(B0, B1, HH, nullptr, 0);
  T(w1[2], HH, HH, WT); G(B1, b1[2], B0, HH, HH, 1);
  T(w2[2], HH, HH, WT); G(B0, b2[2], B1, HH, HH, 1);
  // Layer 3 (reordered): Y = x3 @ w1_3 (no bias); agg in 1024-d with fused b1_3+relu;
  // then h3 @ w2_3 + b2_3 (no relu after last conv).
  T(w1[3], HH, OO, WT); G(B1, nullptr, B0, OO, HH, 0);
  AGG(B0, B1, OO, b1[3], 1);
  T(w2[3], OO, OO, WT); G(B1, b2[3], B0, OO, OO, 0);
  // Heads merged: [wm|wv] -> one N=256 GEMM, f32 split epilogue
  T(wm, OO, LL, WT);
  T(wv, OO, LL, WT + (size_t)LL * OO);
  gemm_bt_kernel<1><<<dim3(2, NN / 128), 256, 0, stream>>>(B0, WT, hb, (void*)out, 256, OO, 0);
  // z = mean + var*eps -> out[0:NL]
  reparam_kernel<<<(NN * LL / 4) / 256, 256, 0, stream>>>(
      out + (size_t)NN * LL, out + (size_t)2 * NN * LL, eps, out);
}

// Round 7
// 975.680 us; speedup vs baseline: 1.3895x; 1.0388x over previous
//
#include <hip/hip_runtime.h>

#define NN 8192
#define EE 262144
#define TT 256
#define HH 2048
#define OO 1024
#define LL 128
#define NW 10

typedef __bf16 bf16_t;
typedef __bf16 bf16x8_t __attribute__((ext_vector_type(8)));
typedef float f32x4_t __attribute__((ext_vector_type(4)));

__device__ __forceinline__ void async16(void* lds, const void* g) {
  __builtin_amdgcn_global_load_lds(
      (const __attribute__((address_space(1))) void*)g,
      (__attribute__((address_space(3))) void*)lds, 16, 0, 0);
}

// Activations: 256-col tiled layout. elem(row,col) at (col>>8)*NN*256 + row*256 + (col&255).

// ---------------- CSR build (dst-major) ----------------
__global__ __launch_bounds__(256) void count_deg_kernel(const int* __restrict__ dst,
                                                        int* __restrict__ deg) {
  int e = blockIdx.x * 256 + threadIdx.x;
  if (e < EE) atomicAdd(&deg[dst[e]], 1);
}

__global__ __launch_bounds__(1024) void scan_kernel(const int* __restrict__ deg,
                                                    int* __restrict__ rs) {
  __shared__ int s[1024];
  int t = threadIdx.x;
  int pre[8];
  int sum = 0;
#pragma unroll
  for (int j = 0; j < 8; ++j) { pre[j] = sum; sum += deg[t * 8 + j]; }
  s[t] = sum;
  __syncthreads();
  for (int off = 1; off < 1024; off <<= 1) {
    int add = (t >= off) ? s[t - off] : 0;
    __syncthreads();
    s[t] += add;
    __syncthreads();
  }
  int base = (t == 0) ? 0 : s[t - 1];
#pragma unroll
  for (int j = 0; j < 8; ++j) rs[t * 8 + j] = base + pre[j];
  if (t == 1023) rs[8192] = s[1023];
}

__global__ __launch_bounds__(256) void fill_csr_kernel(const int* __restrict__ src,
                                                       const int* __restrict__ dst,
                                                       const int* __restrict__ rs,
                                                       int* __restrict__ cur,
                                                       int* __restrict__ csr) {
  int e = blockIdx.x * 256 + threadIdx.x;
  if (e >= EE) return;
  int d = dst[e];
  int p = atomicAdd(&cur[d], 1);
  csr[rs[d] + p] = src[e];
}

// ---------------- merged prep: all 9 weight transposes + x0 cast ----------------
struct WTab {
  const float* src[NW];
  int K[NW];
  int N[NW];
  long long dstOff[NW];
  int tileStart[NW + 1];
  const float* x0;
  bf16_t* castDst;
  int castStart;
};

__global__ __launch_bounds__(256) void prep_all_kernel(WTab tab, bf16_t* __restrict__ WT) {
  int b = blockIdx.x;
  int t = threadIdx.x;
  if (b >= tab.castStart) {
    int i = (b - tab.castStart) * 256 + t;
    f32x4_t a = ((const f32x4_t*)tab.x0)[i * 2];
    f32x4_t bb = ((const f32x4_t*)tab.x0)[i * 2 + 1];
    bf16x8_t o;
#pragma unroll
    for (int j = 0; j < 4; ++j) { o[j] = (bf16_t)a[j]; o[4 + j] = (bf16_t)bb[j]; }
    ((bf16x8_t*)tab.castDst)[i] = o;
    return;
  }
  int wi = 0;
#pragma unroll
  for (int k = 1; k < NW; ++k)
    if (b >= tab.tileStart[k]) wi = k;
  int tt = b - tab.tileStart[wi];
  int K = tab.K[wi], N = tab.N[wi];
  int ntn = N >> 6;
  int n0 = (tt % ntn) * 64, k0 = (tt / ntn) * 64;
  const float* in = tab.src[wi];
  bf16_t* out = WT + tab.dstOff[wi];

  __shared__ float tile[64][65];
  for (int c = t; c < 1024; c += 256) {
    int r = c >> 4, col = (c & 15) * 4;
    f32x4_t v = *(const f32x4_t*)&in[(size_t)(k0 + r) * N + n0 + col];
#pragma unroll
    for (int j = 0; j < 4; ++j) tile[r][col + j] = v[j];
  }
  __syncthreads();
  for (int c = t; c < 512; c += 256) {
    int r = c >> 3, col = (c & 7) * 8;
    bf16x8_t v;
#pragma unroll
    for (int j = 0; j < 8; ++j) v[j] = (bf16_t)tile[col + j][r];
    *(bf16x8_t*)&out[(size_t)(n0 + r) * K + k0 + col] = v;
  }
}

// ---------------- standalone transpose+cast (fallback path) ----------------
__global__ __launch_bounds__(256) void transpose_cast_kernel(const float* __restrict__ in,
                                                             bf16_t* __restrict__ out,
                                                             int K, int N) {
  __shared__ float tile[64][65];
  int n0 = blockIdx.x * 64, k0 = blockIdx.y * 64;
  int t = threadIdx.x;
  for (int c = t; c < 1024; c += 256) {
    int r = c >> 4, col = (c & 15) * 4;
    f32x4_t v = *(const f32x4_t*)&in[(size_t)(k0 + r) * N + n0 + col];
#pragma unroll
    for (int j = 0; j < 4; ++j) tile[r][col + j] = v[j];
  }
  __syncthreads();
  for (int c = t; c < 512; c += 256) {
    int r = c >> 3, col = (c & 7) * 8;
    bf16x8_t v;
#pragma unroll
    for (int j = 0; j < 8; ++j) v[j] = (bf16_t)tile[col + j][r];
    *(bf16x8_t*)&out[(size_t)(n0 + r) * K + k0 + col] = v;
  }
}

__global__ __launch_bounds__(256) void cast_kernel(const float* __restrict__ in,
                                                   bf16_t* __restrict__ out) {
  int i = blockIdx.x * 256 + threadIdx.x;
  f32x4_t a = ((const f32x4_t*)in)[i * 2];
  f32x4_t b = ((const f32x4_t*)in)[i * 2 + 1];
  bf16x8_t o;
#pragma unroll
  for (int j = 0; j < 4; ++j) { o[j] = (bf16_t)a[j]; o[4 + j] = (bf16_t)b[j]; }
  ((bf16x8_t*)out)[i] = o;
}

// ------- layer-0 aggregation, d=256 -------
__global__ __launch_bounds__(64) void agg0_kernel(const bf16_t* __restrict__ x,
                                                  bf16_t* __restrict__ out,
                                                  const int* __restrict__ rs,
                                                  const int* __restrict__ csr) {
  int t = threadIdx.x;
  int node = blockIdx.x * 2 + (t >> 5);
  int c = t & 31;
  const bf16x8_t* xv = (const bf16x8_t*)x;
  bf16x8_t self = xv[(size_t)node * 32 + c];
  float acc[8];
#pragma unroll
  for (int j = 0; j < 8; ++j) acc[j] = (float)self[j];
  int e0 = rs[node], e1 = rs[node + 1];
  int e = e0;
  for (; e + 4 <= e1; e += 4) {
    int s0 = csr[e], s1 = csr[e + 1], s2 = csr[e + 2], s3 = csr[e + 3];
    bf16x8_t v0 = xv[(size_t)s0 * 32 + c];
    bf16x8_t v1 = xv[(size_t)s1 * 32 + c];
    bf16x8_t v2 = xv[(size_t)s2 * 32 + c];
    bf16x8_t v3 = xv[(size_t)s3 * 32 + c];
#pragma unroll
    for (int j = 0; j < 8; ++j)
      acc[j] += (float)v0[j] + (float)v1[j] + (float)v2[j] + (float)v3[j];
  }
  for (; e < e1; ++e) {
    bf16x8_t v = xv[(size_t)csr[e] * 32 + c];
#pragma unroll
    for (int j = 0; j < 8; ++j) acc[j] += (float)v[j];
  }
  bf16x8_t o;
#pragma unroll
  for (int j = 0; j < 8; ++j) o[j] = (bf16_t)acc[j];
  ((bf16x8_t*)out)[(size_t)node * 32 + c] = o;
}

// ------- aggregation over tiled activations; optional fused bias+relu -------
__global__ __launch_bounds__(256) void agg_tiled_kernel(const bf16_t* __restrict__ x,
                                                        bf16_t* __restrict__ out,
                                                        const int* __restrict__ rs,
                                                        const int* __restrict__ csr,
                                                        const float* __restrict__ bias,
                                                        int relu) {
  int t = threadIdx.x;
  int node = blockIdx.x * 8 + (t >> 5);
  int c = t & 31;
  size_t tb = (size_t)blockIdx.y * (NN * 32);
  const bf16x8_t* xv = (const bf16x8_t*)x + tb;
  bf16x8_t self = xv[node * 32 + c];
  float acc[8];
#pragma unroll
  for (int j = 0; j < 8; ++j) acc[j] = (float)self[j];
  int e0 = rs[node], e1 = rs[node + 1];
  int e = e0;
  for (; e + 4 <= e1; e += 4) {
    int s0 = csr[e], s1 = csr[e + 1], s2 = csr[e + 2], s3 = csr[e + 3];
    bf16x8_t v0 = xv[s0 * 32 + c];
    bf16x8_t v1 = xv[s1 * 32 + c];
    bf16x8_t v2 = xv[s2 * 32 + c];
    bf16x8_t v3 = xv[s3 * 32 + c];
#pragma unroll
    for (int j = 0; j < 8; ++j)
      acc[j] += (float)v0[j] + (float)v1[j] + (float)v2[j] + (float)v3[j];
  }
  for (; e < e1; ++e) {
    bf16x8_t v = xv[csr[e] * 32 + c];
#pragma unroll
    for (int j = 0; j < 8; ++j) acc[j] += (float)v[j];
  }
  if (bias) {
    const float* bp = bias + blockIdx.y * 256 + c * 8;
    f32x4_t b0 = *(const f32x4_t*)bp;
    f32x4_t b1 = *(const f32x4_t*)(bp + 4);
#pragma unroll
    for (int j = 0; j < 4; ++j) { acc[j] += b0[j]; acc[4 + j] += b1[j]; }
  }
  if (relu) {
#pragma unroll
    for (int j = 0; j < 8; ++j) acc[j] = fmaxf(acc[j], 0.f);
  }
  bf16x8_t o;
#pragma unroll
  for (int j = 0; j < 8; ++j) o[j] = (bf16_t)acc[j];
  ((bf16x8_t*)out + tb)[node * 32 + c] = o;
}

// ------- GEMM: C = A(tiled) @ Bt^T + bias [+relu]; M == NN fixed -------
template <int CMODE>
__global__ __launch_bounds__(256, 2) void gemm_bt_kernel(
    const bf16_t* __restrict__ A, const bf16_t* __restrict__ Bt,
    const float* __restrict__ bias, void* __restrict__ Cv,
    int N, int K, int relu) {
  __shared__ __align__(16) bf16_t lA[128 * 32];
  __shared__ __align__(16) bf16_t lB[128 * 32];
  const int tid = threadIdx.x;
  const int lane = tid & 63;
  const int wave = tid >> 6;
  const int wm64 = (wave & 1) * 64;
  const int wn64 = (wave >> 1) * 64;
  const int row16 = lane & 15;
  const int quad = lane >> 4;
  const size_t m0 = (size_t)blockIdx.y * 128;
  const size_t n0 = (size_t)blockIdx.x * 128;

  f32x4_t acc[4][4];
#pragma unroll
  for (int i = 0; i < 4; ++i)
#pragma unroll
    for (int j = 0; j < 4; ++j)
#pragma unroll
      for (int r = 0; r < 4; ++r) acc[i][j][r] = 0.f;

  const bf16_t* Bbase = Bt + n0 * K;
  const int r0 = tid >> 2;
  const int r1 = (tid + 256) >> 2;
  const int kc = (tid & 3) * 8;

  for (int kt = 0; kt < K; kt += 32) {
    const bf16_t* Ab = A + ((size_t)(kt >> 8)) * (NN * 256) + (kt & 255) + kc;
    async16(&lA[tid * 8], Ab + (m0 + r0) * 256);
    async16(&lA[(tid + 256) * 8], Ab + (m0 + r1) * 256);
    async16(&lB[tid * 8], Bbase + (size_t)r0 * K + kt + kc);
    async16(&lB[(tid + 256) * 8], Bbase + (size_t)r1 * K + kt + kc);
    __syncthreads();
    bf16x8_t af[4], bfr[4];
#pragma unroll
    for (int i = 0; i < 4; ++i)
      af[i] = *(const bf16x8_t*)&lA[(wm64 + i * 16 + row16) * 32 + quad * 8];
#pragma unroll
    for (int i = 0; i < 4; ++i)
      bfr[i] = *(const bf16x8_t*)&lB[(wn64 + i * 16 + row16) * 32 + quad * 8];
#pragma unroll
    for (int i = 0; i < 4; ++i)
#pragma unroll
      for (int j = 0; j < 4; ++j)
        acc[i][j] = __builtin_amdgcn_mfma_f32_16x16x32_bf16(af[i], bfr[j], acc[i][j], 0, 0, 0);
    __syncthreads();
  }

  // C/D layout: col = lane&15, row = quad*4 + reg  [verified m89/m91]
#pragma unroll
  for (int i = 0; i < 4; ++i) {
    size_t row = m0 + wm64 + i * 16 + quad * 4;
#pragma unroll
    for (int j = 0; j < 4; ++j) {
      int col = (int)n0 + wn64 + j * 16 + row16;
      float b = bias ? bias[col] : 0.f;
      if (CMODE == 0) {
        size_t cb = ((size_t)(col >> 8)) * (NN * 256) + (col & 255);
#pragma unroll
        for (int r = 0; r < 4; ++r) {
          float o = acc[i][j][r] + b;
          if (relu) o = fmaxf(o, 0.f);
          ((bf16_t*)Cv)[cb + (row + r) * 256] = (bf16_t)o;
        }
      } else {
        int sel = col >> 7;
        int c2 = col & 127;
        float* dstp = (float*)Cv + (size_t)(1 + sel) * NN * LL + c2;
#pragma unroll
        for (int r = 0; r < 4; ++r) {
          dstp[(row + r) * LL] = acc[i][j][r] + b;
        }
      }
    }
  }
}

// ---------------- z = mean + var*eps (f32) ----------------
__global__ __launch_bounds__(256) void reparam_kernel(const float* __restrict__ mean,
                                                      const float* __restrict__ var,
                                                      const float* __restrict__ eps,
                                                      float* __restrict__ z) {
  int i = blockIdx.x * 256 + threadIdx.x;
  f32x4_t m = ((const f32x4_t*)mean)[i];
  f32x4_t v = ((const f32x4_t*)var)[i];
  f32x4_t e = ((const f32x4_t*)eps)[i];
  f32x4_t o;
#pragma unroll
  for (int j = 0; j < 4; ++j) o[j] = m[j] + v[j] * e[j];
  ((f32x4_t*)z)[i] = o;
}

extern "C" void kernel_launch(void* const* d_in, const int* in_sizes, int n_in,
                              void* d_out, int out_size, void* d_ws, size_t ws_size,
                              hipStream_t stream) {
  (void)in_sizes; (void)n_in; (void)out_size;
  const float* x0 = (const float*)d_in[0];
  const int* ei = (const int*)d_in[1];
  const int* src = ei;
  const int* dst = ei + EE;
  const float* w1[4] = {(const float*)d_in[2], (const float*)d_in[6],
                        (const float*)d_in[10], (const float*)d_in[14]};
  const float* b1[4] = {(const float*)d_in[3], (const float*)d_in[7],
                        (const float*)d_in[11], (const float*)d_in[15]};
  const float* w2[4] = {(const float*)d_in[4], (const float*)d_in[8],
                        (const float*)d_in[12], (const float*)d_in[16]};
  const float* b2[4] = {(const float*)d_in[5], (const float*)d_in[9],
                        (const float*)d_in[13], (const float*)d_in[17]};
  const float* wm = (const float*)d_in[18];
  const float* bm = (const float*)d_in[19];
  const float* wv = (const float*)d_in[20];
  const float* bv = (const float*)d_in[21];
  const float* eps = (const float*)d_in[22];
  float* out = (float*)d_out;

  char* ws = (char*)d_ws;
  bf16_t* B0 = (bf16_t*)(ws);
  bf16_t* B1 = (bf16_t*)(ws + 33554432);
  bf16_t* WT = (bf16_t*)(ws + 67108864);

  // Per-weight WT slot offsets (bf16 elems), order: w1_0,w2_0,w1_1,w2_1,w1_2,w2_2,w1_3,w2_3,wm,wv
  const long long soff[NW] = {0LL, 524288LL, 4718592LL, 8912896LL, 13107200LL,
                              17301504LL, 21495808LL, 23592960LL, 24641536LL, 24772608LL};
  const size_t wtBytesFull = 24903680ULL * 2ULL;          // 49.8 MB
  const size_t needFull = 67108864ULL + wtBytesFull + 2097152ULL;  // +2MB CSR area
  bool full = ws_size >= needFull;

  size_t csrBase = full ? (67108864ULL + wtBytesFull) : 75497472ULL;
  int* deg = (int*)(ws + csrBase);
  int* cur = deg + 8192;
  int* rs = deg + 16384;
  int* csr = deg + 16384 + 8200;
  float* hb = (float*)(csr + 262144);

  hipMemcpyAsync(hb, bm, 128 * sizeof(float), hipMemcpyDeviceToDevice, stream);
  hipMemcpyAsync(hb + 128, bv, 128 * sizeof(float), hipMemcpyDeviceToDevice, stream);

  auto AGG = [&](const bf16_t* in, bf16_t* outp, int d, const float* bias, int relu) {
    agg_tiled_kernel<<<dim3(NN / 8, d / 256), 256, 0, stream>>>(in, outp, rs, csr, bias, relu);
  };

  if (full) {
    // ---- merged prep: all transposes + x0 cast in one dispatch ----
    WTab tab;
    const float* srcs[NW] = {w1[0], w2[0], w1[1], w2[1], w1[2], w2[2], w1[3], w2[3], wm, wv};
    const int Ks[NW] = {TT, HH, HH, HH, HH, HH, HH, OO, OO, OO};
    const int Ns[NW] = {HH, HH, HH, HH, HH, HH, OO, OO, LL, LL};
    int cum = 0;
    for (int i = 0; i < NW; ++i) {
      tab.src[i] = srcs[i];
      tab.K[i] = Ks[i];
      tab.N[i] = Ns[i];
      tab.dstOff[i] = soff[i];
      tab.tileStart[i] = cum;
      cum += (Ns[i] >> 6) * (Ks[i] >> 6);
    }
    tab.tileStart[NW] = cum;       // 6080
    tab.castStart = cum;
    tab.x0 = x0;
    tab.castDst = B0;
    int totalBlocks = cum + (NN * TT / 8) / 256;   // + 1024 cast blocks
    prep_all_kernel<<<totalBlocks, 256, 0, stream>>>(tab, WT);

    hipMemsetAsync(deg, 0, 2 * 8192 * sizeof(int), stream);
    count_deg_kernel<<<EE / 256, 256, 0, stream>>>(dst, deg);
    scan_kernel<<<1, 1024, 0, stream>>>(deg, rs);
    fill_csr_kernel<<<EE / 256, 256, 0, stream>>>(src, dst, rs, cur, csr);

    auto G = [&](const bf16_t* A, int wi, const float* bias, bf16_t* C, int Nn, int K, int relu) {
      gemm_bt_kernel<0><<<dim3(Nn / 128, NN / 128), 256, 0, stream>>>(
          A, WT + soff[wi], bias, (void*)C, Nn, K, relu);
    };

    agg0_kernel<<<NN / 2, 64, 0, stream>>>(B0, B1, rs, csr);
    G(B1, 0, b1[0], B0, HH, TT, 1);
    G(B0, 1, b2[0], B1, HH, HH, 1);
    AGG(B1, B0, HH, nullptr, 0);
    G(B0, 2, b1[1], B1, HH, HH, 1);
    G(B1, 3, b2[1], B0, HH, HH, 1);
    AGG(B0, B1, HH, nullptr, 0);
    G(B1, 4, b1[2], B0, HH, HH, 1);
    G(B0, 5, b2[2], B1, HH, HH, 1);
    // Layer 3 reordered: Y = x3 @ w1_3 (no bias); agg 1024-d fused b1_3+relu; then w2_3.
    G(B1, 6, nullptr, B0, OO, HH, 0);
    AGG(B0, B1, OO, b1[3], 1);
    G(B1, 7, b2[3], B0, OO, OO, 0);
    // Heads: wm|wv slots are adjacent -> one N=256 GEMM, f32 split epilogue
    gemm_bt_kernel<1><<<dim3(2, NN / 128), 256, 0, stream>>>(
        B0, WT + soff[8], hb, (void*)out, 256, OO, 0);
  } else {
    // ---- fallback: round-6 interleaved scheme (shared 8.4MB WT) ----
    hipMemsetAsync(deg, 0, 2 * 8192 * sizeof(int), stream);
    count_deg_kernel<<<EE / 256, 256, 0, stream>>>(dst, deg);
    scan_kernel<<<1, 1024, 0, stream>>>(deg, rs);
    fill_csr_kernel<<<EE / 256, 256, 0, stream>>>(src, dst, rs, cur, csr);

    auto T = [&](const float* w, int K, int Nn, bf16_t* dstw) {
      transpose_cast_kernel<<<dim3(Nn / 64, K / 64), 256, 0, stream>>>(w, dstw, K, Nn);
    };
    auto G = [&](const bf16_t* A, const float* bias, bf16_t* C, int Nn, int K, int relu) {
      gemm_bt_kernel<0><<<dim3(Nn / 128, NN / 128), 256, 0, stream>>>(A, WT, bias, (void*)C, Nn, K, relu);
    };

    cast_kernel<<<(NN * TT / 8) / 256, 256, 0, stream>>>(x0, B0);
    agg0_kernel<<<NN / 2, 64, 0, stream>>>(B0, B1, rs, csr);
    T(w1[0], TT, HH, WT); G(B1, b1[0], B0, HH, TT, 1);
    T(w2[0], HH, HH, WT); G(B0, b2[0], B1, HH, HH, 1);
    AGG(B1, B0, HH, nullptr, 0);
    T(w1[1], HH, HH, WT); G(B0, b1[1], B1, HH, HH, 1);
    T(w2[1], HH, HH, WT); G(B1, b2[1], B0, HH, HH, 1);
    AGG(B0, B1, HH, nullptr, 0);
    T(w1[2], HH, HH, WT); G(B1, b1[2], B0, HH, HH, 1);
    T(w2[2], HH, HH, WT); G(B0, b2[2], B1, HH, HH, 1);
    T(w1[3], HH, OO, WT); G(B1, nullptr, B0, OO, HH, 0);
    AGG(B0, B1, OO, b1[3], 1);
    T(w2[3], OO, OO, WT); G(B1, b2[3], B0, OO, OO, 0);
    T(wm, OO, LL, WT);
    T(wv, OO, LL, WT + (size_t)LL * OO);
    gemm_bt_kernel<1><<<dim3(2, NN / 128), 256, 0, stream>>>(B0, WT, hb, (void*)out, 256, OO, 0);
  }

  reparam_kernel<<<(NN * LL / 4) / 256, 256, 0, stream>>>(
      out + (size_t)NN * LL, out + (size_t)2 * NN * LL, eps, out);
}

// Round 8
// 898.919 us; speedup vs baseline: 1.5081x; 1.0854x over previous
//
#include <hip/hip_runtime.h>

#define NN 8192
#define EE 262144
#define TT 256
#define HH 2048
#define OO 1024
#define LL 128
#define NW 10

typedef __bf16 bf16_t;
typedef __bf16 bf16x8_t __attribute__((ext_vector_type(8)));
typedef float f32x4_t __attribute__((ext_vector_type(4)));

__device__ __forceinline__ void async16(void* lds, const void* g) {
  __builtin_amdgcn_global_load_lds(
      (const __attribute__((address_space(1))) void*)g,
      (__attribute__((address_space(3))) void*)lds, 16, 0, 0);
}

// Activations: 256-col tiled layout. elem(row,col) at (col>>8)*NN*256 + row*256 + (col&255).

// ---------------- CSR build (dst-major) ----------------
__global__ __launch_bounds__(256) void count_deg_kernel(const int* __restrict__ dst,
                                                        int* __restrict__ deg) {
  int e = blockIdx.x * 256 + threadIdx.x;
  if (e < EE) atomicAdd(&deg[dst[e]], 1);
}

__global__ __launch_bounds__(1024) void scan_kernel(const int* __restrict__ deg,
                                                    int* __restrict__ rs) {
  __shared__ int s[1024];
  int t = threadIdx.x;
  int pre[8];
  int sum = 0;
#pragma unroll
  for (int j = 0; j < 8; ++j) { pre[j] = sum; sum += deg[t * 8 + j]; }
  s[t] = sum;
  __syncthreads();
  for (int off = 1; off < 1024; off <<= 1) {
    int add = (t >= off) ? s[t - off] : 0;
    __syncthreads();
    s[t] += add;
    __syncthreads();
  }
  int base = (t == 0) ? 0 : s[t - 1];
#pragma unroll
  for (int j = 0; j < 8; ++j) rs[t * 8 + j] = base + pre[j];
  if (t == 1023) rs[8192] = s[1023];
}

__global__ __launch_bounds__(256) void fill_csr_kernel(const int* __restrict__ src,
                                                       const int* __restrict__ dst,
                                                       const int* __restrict__ rs,
                                                       int* __restrict__ cur,
                                                       int* __restrict__ csr) {
  int e = blockIdx.x * 256 + threadIdx.x;
  if (e >= EE) return;
  int d = dst[e];
  int p = atomicAdd(&cur[d], 1);
  csr[rs[d] + p] = src[e];
}

// ---------------- merged prep: all 9 weight transposes + x0 cast ----------------
struct WTab {
  const float* src[NW];
  int K[NW];
  int N[NW];
  long long dstOff[NW];
  int tileStart[NW + 1];
  const float* x0;
  bf16_t* castDst;
  int castStart;
};

__global__ __launch_bounds__(256) void prep_all_kernel(WTab tab, bf16_t* __restrict__ WT) {
  int b = blockIdx.x;
  int t = threadIdx.x;
  if (b >= tab.castStart) {
    int i = (b - tab.castStart) * 256 + t;
    f32x4_t a = ((const f32x4_t*)tab.x0)[i * 2];
    f32x4_t bb = ((const f32x4_t*)tab.x0)[i * 2 + 1];
    bf16x8_t o;
#pragma unroll
    for (int j = 0; j < 4; ++j) { o[j] = (bf16_t)a[j]; o[4 + j] = (bf16_t)bb[j]; }
    ((bf16x8_t*)tab.castDst)[i] = o;
    return;
  }
  int wi = 0;
#pragma unroll
  for (int k = 1; k < NW; ++k)
    if (b >= tab.tileStart[k]) wi = k;
  int tt = b - tab.tileStart[wi];
  int K = tab.K[wi], N = tab.N[wi];
  int ntn = N >> 6;
  int n0 = (tt % ntn) * 64, k0 = (tt / ntn) * 64;
  const float* in = tab.src[wi];
  bf16_t* out = WT + tab.dstOff[wi];

  __shared__ float tile[64][65];
  for (int c = t; c < 1024; c += 256) {
    int r = c >> 4, col = (c & 15) * 4;
    f32x4_t v = *(const f32x4_t*)&in[(size_t)(k0 + r) * N + n0 + col];
#pragma unroll
    for (int j = 0; j < 4; ++j) tile[r][col + j] = v[j];
  }
  __syncthreads();
  for (int c = t; c < 512; c += 256) {
    int r = c >> 3, col = (c & 7) * 8;
    bf16x8_t v;
#pragma unroll
    for (int j = 0; j < 8; ++j) v[j] = (bf16_t)tile[col + j][r];
    *(bf16x8_t*)&out[(size_t)(n0 + r) * K + k0 + col] = v;
  }
}

// ---------------- standalone transpose+cast (fallback path) ----------------
__global__ __launch_bounds__(256) void transpose_cast_kernel(const float* __restrict__ in,
                                                             bf16_t* __restrict__ out,
                                                             int K, int N) {
  __shared__ float tile[64][65];
  int n0 = blockIdx.x * 64, k0 = blockIdx.y * 64;
  int t = threadIdx.x;
  for (int c = t; c < 1024; c += 256) {
    int r = c >> 4, col = (c & 15) * 4;
    f32x4_t v = *(const f32x4_t*)&in[(size_t)(k0 + r) * N + n0 + col];
#pragma unroll
    for (int j = 0; j < 4; ++j) tile[r][col + j] = v[j];
  }
  __syncthreads();
  for (int c = t; c < 512; c += 256) {
    int r = c >> 3, col = (c & 7) * 8;
    bf16x8_t v;
#pragma unroll
    for (int j = 0; j < 8; ++j) v[j] = (bf16_t)tile[col + j][r];
    *(bf16x8_t*)&out[(size_t)(n0 + r) * K + k0 + col] = v;
  }
}

__global__ __launch_bounds__(256) void cast_kernel(const float* __restrict__ in,
                                                   bf16_t* __restrict__ out) {
  int i = blockIdx.x * 256 + threadIdx.x;
  f32x4_t a = ((const f32x4_t*)in)[i * 2];
  f32x4_t b = ((const f32x4_t*)in)[i * 2 + 1];
  bf16x8_t o;
#pragma unroll
  for (int j = 0; j < 4; ++j) { o[j] = (bf16_t)a[j]; o[4 + j] = (bf16_t)b[j]; }
  ((bf16x8_t*)out)[i] = o;
}

// ------- layer-0 aggregation, d=256 -------
__global__ __launch_bounds__(64) void agg0_kernel(const bf16_t* __restrict__ x,
                                                  bf16_t* __restrict__ out,
                                                  const int* __restrict__ rs,
                                                  const int* __restrict__ csr) {
  int t = threadIdx.x;
  int node = blockIdx.x * 2 + (t >> 5);
  int c = t & 31;
  const bf16x8_t* xv = (const bf16x8_t*)x;
  bf16x8_t self = xv[(size_t)node * 32 + c];
  float acc[8];
#pragma unroll
  for (int j = 0; j < 8; ++j) acc[j] = (float)self[j];
  int e0 = rs[node], e1 = rs[node + 1];
  int e = e0;
  for (; e + 4 <= e1; e += 4) {
    int s0 = csr[e], s1 = csr[e + 1], s2 = csr[e + 2], s3 = csr[e + 3];
    bf16x8_t v0 = xv[(size_t)s0 * 32 + c];
    bf16x8_t v1 = xv[(size_t)s1 * 32 + c];
    bf16x8_t v2 = xv[(size_t)s2 * 32 + c];
    bf16x8_t v3 = xv[(size_t)s3 * 32 + c];
#pragma unroll
    for (int j = 0; j < 8; ++j)
      acc[j] += (float)v0[j] + (float)v1[j] + (float)v2[j] + (float)v3[j];
  }
  for (; e < e1; ++e) {
    bf16x8_t v = xv[(size_t)csr[e] * 32 + c];
#pragma unroll
    for (int j = 0; j < 8; ++j) acc[j] += (float)v[j];
  }
  bf16x8_t o;
#pragma unroll
  for (int j = 0; j < 8; ++j) o[j] = (bf16_t)acc[j];
  ((bf16x8_t*)out)[(size_t)node * 32 + c] = o;
}

// ------- aggregation over tiled activations, XCD-pinned tiles -------
// 1-D grid, tile = blockIdx & tmask: consecutive blocks round-robin across the 8 XCDs,
// so tile t stays on XCD t (ntiles=8) and its 4 MB block stays resident in that XCD's L2.
__global__ __launch_bounds__(256) void agg_tiled_kernel(const bf16_t* __restrict__ x,
                                                        bf16_t* __restrict__ out,
                                                        const int* __restrict__ rs,
                                                        const int* __restrict__ csr,
                                                        const float* __restrict__ bias,
                                                        int relu, int tmask, int tshift) {
  int t = threadIdx.x;
  int tile = blockIdx.x & tmask;
  int ng = blockIdx.x >> tshift;
  int node = ng * 8 + (t >> 5);
  int c = t & 31;
  size_t tb = (size_t)tile * (NN * 32);
  const bf16x8_t* xv = (const bf16x8_t*)x + tb;
  bf16x8_t self = xv[node * 32 + c];
  float acc[8];
#pragma unroll
  for (int j = 0; j < 8; ++j) acc[j] = (float)self[j];
  int e0 = rs[node], e1 = rs[node + 1];
  int e = e0;
  for (; e + 4 <= e1; e += 4) {
    int s0 = csr[e], s1 = csr[e + 1], s2 = csr[e + 2], s3 = csr[e + 3];
    bf16x8_t v0 = xv[s0 * 32 + c];
    bf16x8_t v1 = xv[s1 * 32 + c];
    bf16x8_t v2 = xv[s2 * 32 + c];
    bf16x8_t v3 = xv[s3 * 32 + c];
#pragma unroll
    for (int j = 0; j < 8; ++j)
      acc[j] += (float)v0[j] + (float)v1[j] + (float)v2[j] + (float)v3[j];
  }
  for (; e < e1; ++e) {
    bf16x8_t v = xv[csr[e] * 32 + c];
#pragma unroll
    for (int j = 0; j < 8; ++j) acc[j] += (float)v[j];
  }
  if (bias) {
    const float* bp = bias + tile * 256 + c * 8;
    f32x4_t b0 = *(const f32x4_t*)bp;
    f32x4_t b1 = *(const f32x4_t*)(bp + 4);
#pragma unroll
    for (int j = 0; j < 4; ++j) { acc[j] += b0[j]; acc[4 + j] += b1[j]; }
  }
  if (relu) {
#pragma unroll
    for (int j = 0; j < 8; ++j) acc[j] = fmaxf(acc[j], 0.f);
  }
  bf16x8_t o;
#pragma unroll
  for (int j = 0; j < 8; ++j) o[j] = (bf16_t)acc[j];
  ((bf16x8_t*)out + tb)[node * 32 + c] = o;
}

// ------- GEMM: C = A(tiled) @ Bt^T + bias [+relu]; M == NN fixed -------
// CMODE 0: bf16 tiled output. CMODE 1: head f32 split output (col<128 -> mean + biasA,
// col>=128 -> var + biasB).
template <int CMODE>
__global__ __launch_bounds__(256, 2) void gemm_bt_kernel(
    const bf16_t* __restrict__ A, const bf16_t* __restrict__ Bt,
    const float* __restrict__ bias, const float* __restrict__ biasB,
    void* __restrict__ Cv, int N, int K, int relu) {
  __shared__ __align__(16) bf16_t lA[128 * 32];
  __shared__ __align__(16) bf16_t lB[128 * 32];
  const int tid = threadIdx.x;
  const int lane = tid & 63;
  const int wave = tid >> 6;
  const int wm64 = (wave & 1) * 64;
  const int wn64 = (wave >> 1) * 64;
  const int row16 = lane & 15;
  const int quad = lane >> 4;
  const size_t m0 = (size_t)blockIdx.y * 128;
  const size_t n0 = (size_t)blockIdx.x * 128;

  f32x4_t acc[4][4];
#pragma unroll
  for (int i = 0; i < 4; ++i)
#pragma unroll
    for (int j = 0; j < 4; ++j)
#pragma unroll
      for (int r = 0; r < 4; ++r) acc[i][j][r] = 0.f;

  const bf16_t* Bbase = Bt + n0 * K;
  const int r0 = tid >> 2;
  const int r1 = (tid + 256) >> 2;
  const int kc = (tid & 3) * 8;

  for (int kt = 0; kt < K; kt += 32) {
    const bf16_t* Ab = A + ((size_t)(kt >> 8)) * (NN * 256) + (kt & 255) + kc;
    async16(&lA[tid * 8], Ab + (m0 + r0) * 256);
    async16(&lA[(tid + 256) * 8], Ab + (m0 + r1) * 256);
    async16(&lB[tid * 8], Bbase + (size_t)r0 * K + kt + kc);
    async16(&lB[(tid + 256) * 8], Bbase + (size_t)r1 * K + kt + kc);
    __syncthreads();
    bf16x8_t af[4], bfr[4];
#pragma unroll
    for (int i = 0; i < 4; ++i)
      af[i] = *(const bf16x8_t*)&lA[(wm64 + i * 16 + row16) * 32 + quad * 8];
#pragma unroll
    for (int i = 0; i < 4; ++i)
      bfr[i] = *(const bf16x8_t*)&lB[(wn64 + i * 16 + row16) * 32 + quad * 8];
#pragma unroll
    for (int i = 0; i < 4; ++i)
#pragma unroll
      for (int j = 0; j < 4; ++j)
        acc[i][j] = __builtin_amdgcn_mfma_f32_16x16x32_bf16(af[i], bfr[j], acc[i][j], 0, 0, 0);
    __syncthreads();
  }

  // C/D layout: col = lane&15, row = quad*4 + reg  [verified m89/m91]
#pragma unroll
  for (int i = 0; i < 4; ++i) {
    size_t row = m0 + wm64 + i * 16 + quad * 4;
#pragma unroll
    for (int j = 0; j < 4; ++j) {
      int col = (int)n0 + wn64 + j * 16 + row16;
      if (CMODE == 0) {
        float b = bias ? bias[col] : 0.f;
        size_t cb = ((size_t)(col >> 8)) * (NN * 256) + (col & 255);
#pragma unroll
        for (int r = 0; r < 4; ++r) {
          float o = acc[i][j][r] + b;
          if (relu) o = fmaxf(o, 0.f);
          ((bf16_t*)Cv)[cb + (row + r) * 256] = (bf16_t)o;
        }
      } else {
        int sel = col >> 7;
        int c2 = col & 127;
        float b = sel ? biasB[c2] : bias[c2];
        float* dstp = (float*)Cv + (size_t)(1 + sel) * NN * LL + c2;
#pragma unroll
        for (int r = 0; r < 4; ++r) {
          dstp[(row + r) * LL] = acc[i][j][r] + b;
        }
      }
    }
  }
}

// ---------------- z = mean + var*eps (f32) ----------------
__global__ __launch_bounds__(256) void reparam_kernel(const float* __restrict__ mean,
                                                      const float* __restrict__ var,
                                                      const float* __restrict__ eps,
                                                      float* __restrict__ z) {
  int i = blockIdx.x * 256 + threadIdx.x;
  f32x4_t m = ((const f32x4_t*)mean)[i];
  f32x4_t v = ((const f32x4_t*)var)[i];
  f32x4_t e = ((const f32x4_t*)eps)[i];
  f32x4_t o;
#pragma unroll
  for (int j = 0; j < 4; ++j) o[j] = m[j] + v[j] * e[j];
  ((f32x4_t*)z)[i] = o;
}

extern "C" void kernel_launch(void* const* d_in, const int* in_sizes, int n_in,
                              void* d_out, int out_size, void* d_ws, size_t ws_size,
                              hipStream_t stream) {
  (void)in_sizes; (void)n_in; (void)out_size;
  const float* x0 = (const float*)d_in[0];
  const int* ei = (const int*)d_in[1];
  const int* src = ei;
  const int* dst = ei + EE;
  const float* w1[4] = {(const float*)d_in[2], (const float*)d_in[6],
                        (const float*)d_in[10], (const float*)d_in[14]};
  const float* b1[4] = {(const float*)d_in[3], (const float*)d_in[7],
                        (const float*)d_in[11], (const float*)d_in[15]};
  const float* w2[4] = {(const float*)d_in[4], (const float*)d_in[8],
                        (const float*)d_in[12], (const float*)d_in[16]};
  const float* b2[4] = {(const float*)d_in[5], (const float*)d_in[9],
                        (const float*)d_in[13], (const float*)d_in[17]};
  const float* wm = (const float*)d_in[18];
  const float* bm = (const float*)d_in[19];
  const float* wv = (const float*)d_in[20];
  const float* bv = (const float*)d_in[21];
  const float* eps = (const float*)d_in[22];
  float* out = (float*)d_out;

  char* ws = (char*)d_ws;
  bf16_t* B0 = (bf16_t*)(ws);
  bf16_t* B1 = (bf16_t*)(ws + 33554432);
  bf16_t* WT = (bf16_t*)(ws + 67108864);

  // Per-weight WT slot offsets (bf16 elems), order: w1_0,w2_0,w1_1,w2_1,w1_2,w2_2,w1_3,w2_3,wm,wv
  const long long soff[NW] = {0LL, 524288LL, 4718592LL, 8912896LL, 13107200LL,
                              17301504LL, 21495808LL, 23592960LL, 24641536LL, 24772608LL};
  const size_t wtBytesFull = 24903680ULL * 2ULL;          // 49.8 MB
  const size_t needFull = 67108864ULL + wtBytesFull + 2097152ULL;
  bool full = ws_size >= needFull;

  size_t csrBase = full ? (67108864ULL + wtBytesFull) : 75497472ULL;
  int* deg = (int*)(ws + csrBase);
  int* cur = deg + 8192;
  int* rs = deg + 16384;
  int* csr = deg + 16384 + 8200;

  auto AGG = [&](const bf16_t* in, bf16_t* outp, int d, const float* bias, int relu) {
    int ntiles = d >> 8;
    int tshift = (ntiles == 8) ? 3 : 2;
    agg_tiled_kernel<<<(NN / 8) * ntiles, 256, 0, stream>>>(in, outp, rs, csr, bias, relu,
                                                            ntiles - 1, tshift);
  };

  if (full) {
    // ---- merged prep: all transposes + x0 cast in one dispatch ----
    WTab tab;
    const float* srcs[NW] = {w1[0], w2[0], w1[1], w2[1], w1[2], w2[2], w1[3], w2[3], wm, wv};
    const int Ks[NW] = {TT, HH, HH, HH, HH, HH, HH, OO, OO, OO};
    const int Ns[NW] = {HH, HH, HH, HH, HH, HH, OO, OO, LL, LL};
    int cum = 0;
    for (int i = 0; i < NW; ++i) {
      tab.src[i] = srcs[i];
      tab.K[i] = Ks[i];
      tab.N[i] = Ns[i];
      tab.dstOff[i] = soff[i];
      tab.tileStart[i] = cum;
      cum += (Ns[i] >> 6) * (Ks[i] >> 6);
    }
    tab.tileStart[NW] = cum;
    tab.castStart = cum;
    tab.x0 = x0;
    tab.castDst = B0;
    int totalBlocks = cum + (NN * TT / 8) / 256;
    prep_all_kernel<<<totalBlocks, 256, 0, stream>>>(tab, WT);

    hipMemsetAsync(deg, 0, 2 * 8192 * sizeof(int), stream);
    count_deg_kernel<<<EE / 256, 256, 0, stream>>>(dst, deg);
    scan_kernel<<<1, 1024, 0, stream>>>(deg, rs);
    fill_csr_kernel<<<EE / 256, 256, 0, stream>>>(src, dst, rs, cur, csr);

    auto G = [&](const bf16_t* A, int wi, const float* bias, bf16_t* C, int Nn, int K, int relu) {
      gemm_bt_kernel<0><<<dim3(Nn / 128, NN / 128), 256, 0, stream>>>(
          A, WT + soff[wi], bias, nullptr, (void*)C, Nn, K, relu);
    };

    agg0_kernel<<<NN / 2, 64, 0, stream>>>(B0, B1, rs, csr);
    G(B1, 0, b1[0], B0, HH, TT, 1);
    G(B0, 1, b2[0], B1, HH, HH, 1);
    AGG(B1, B0, HH, nullptr, 0);
    G(B0, 2, b1[1], B1, HH, HH, 1);
    G(B1, 3, b2[1], B0, HH, HH, 1);
    AGG(B0, B1, HH, nullptr, 0);
    G(B1, 4, b1[2], B0, HH, HH, 1);
    G(B0, 5, b2[2], B1, HH, HH, 1);
    // Layer 3 reordered: Y = x3 @ w1_3 (no bias); agg 1024-d fused b1_3+relu; then w2_3.
    G(B1, 6, nullptr, B0, OO, HH, 0);
    AGG(B0, B1, OO, b1[3], 1);
    G(B1, 7, b2[3], B0, OO, OO, 0);
    // Heads: wm|wv slots adjacent -> one N=256 GEMM, f32 split epilogue, direct bm/bv
    gemm_bt_kernel<1><<<dim3(2, NN / 128), 256, 0, stream>>>(
        B0, WT + soff[8], bm, bv, (void*)out, 256, OO, 0);
  } else {
    // ---- fallback: interleaved scheme (shared 8.4MB WT) ----
    hipMemsetAsync(deg, 0, 2 * 8192 * sizeof(int), stream);
    count_deg_kernel<<<EE / 256, 256, 0, stream>>>(dst, deg);
    scan_kernel<<<1, 1024, 0, stream>>>(deg, rs);
    fill_csr_kernel<<<EE / 256, 256, 0, stream>>>(src, dst, rs, cur, csr);

    auto T = [&](const float* w, int K, int Nn, bf16_t* dstw) {
      transpose_cast_kernel<<<dim3(Nn / 64, K / 64), 256, 0, stream>>>(w, dstw, K, Nn);
    };
    auto G = [&](const bf16_t* A, const float* bias, bf16_t* C, int Nn, int K, int relu) {
      gemm_bt_kernel<0><<<dim3(Nn / 128, NN / 128), 256, 0, stream>>>(
          A, WT, bias, nullptr, (void*)C, Nn, K, relu);
    };

    cast_kernel<<<(NN * TT / 8) / 256, 256, 0, stream>>>(x0, B0);
    agg0_kernel<<<NN / 2, 64, 0, stream>>>(B0, B1, rs, csr);
    T(w1[0], TT, HH, WT); G(B1, b1[0], B0, HH, TT, 1);
    T(w2[0], HH, HH, WT); G(B0, b2[0], B1, HH, HH, 1);
    AGG(B1, B0, HH, nullptr, 0);
    T(w1[1], HH, HH, WT); G(B0, b1[1], B1, HH, HH, 1);
    T(w2[1], HH, HH, WT); G(B1, b2[1], B0, HH, HH, 1);
    AGG(B0, B1, HH, nullptr, 0);
    T(w1[2], HH, HH, WT); G(B1, b1[2], B0, HH, HH, 1);
    T(w2[2], HH, HH, WT); G(B0, b2[2], B1, HH, HH, 1);
    T(w1[3], HH, OO, WT); G(B1, nullptr, B0, OO, HH, 0);
    AGG(B0, B1, OO, b1[3], 1);
    T(w2[3], OO, OO, WT); G(B1, b2[3], B0, OO, OO, 0);
    T(wm, OO, LL, WT);
    T(wv, OO, LL, WT + (size_t)LL * OO);
    gemm_bt_kernel<1><<<dim3(2, NN / 128), 256, 0, stream>>>(
        B0, WT, bm, bv, (void*)out, 256, OO, 0);
  }

  reparam_kernel<<<(NN * LL / 4) / 256, 256, 0, stream>>>(
      out + (size_t)NN * LL, out + (size_t)2 * NN * LL, eps, out);
}

// Round 9
// 862.587 us; speedup vs baseline: 1.5716x; 1.0421x over previous
//
#include <hip/hip_runtime.h>

#define NN 8192
#define EE 262144
#define TT 256
#define HH 2048
#define OO 1024
#define LL 128
#define NW 10

typedef __bf16 bf16_t;
typedef __bf16 bf16x8_t __attribute__((ext_vector_type(8)));
typedef float f32x4_t __attribute__((ext_vector_type(4)));

__device__ __forceinline__ void async16(void* lds, const void* g) {
  __builtin_amdgcn_global_load_lds(
      (const __attribute__((address_space(1))) void*)g,
      (__attribute__((address_space(3))) void*)lds, 16, 0, 0);
}

// Activations: 256-col tiled layout. elem(row,col) at (col>>8)*NN*256 + row*256 + (col&255).
// Empirically validated on this box (r8): workgroup -> XCD assignment is blockIdx % 8.

// ---------------- CSR build (dst-major) ----------------
__global__ __launch_bounds__(256) void count_deg_kernel(const int* __restrict__ dst,
                                                        int* __restrict__ deg) {
  int e = blockIdx.x * 256 + threadIdx.x;
  if (e < EE) atomicAdd(&deg[dst[e]], 1);
}

__global__ __launch_bounds__(1024) void scan_kernel(const int* __restrict__ deg,
                                                    int* __restrict__ rs) {
  __shared__ int s[1024];
  int t = threadIdx.x;
  int pre[8];
  int sum = 0;
#pragma unroll
  for (int j = 0; j < 8; ++j) { pre[j] = sum; sum += deg[t * 8 + j]; }
  s[t] = sum;
  __syncthreads();
  for (int off = 1; off < 1024; off <<= 1) {
    int add = (t >= off) ? s[t - off] : 0;
    __syncthreads();
    s[t] += add;
    __syncthreads();
  }
  int base = (t == 0) ? 0 : s[t - 1];
#pragma unroll
  for (int j = 0; j < 8; ++j) rs[t * 8 + j] = base + pre[j];
  if (t == 1023) rs[8192] = s[1023];
}

__global__ __launch_bounds__(256) void fill_csr_kernel(const int* __restrict__ src,
                                                       const int* __restrict__ dst,
                                                       const int* __restrict__ rs,
                                                       int* __restrict__ cur,
                                                       int* __restrict__ csr) {
  int e = blockIdx.x * 256 + threadIdx.x;
  if (e >= EE) return;
  int d = dst[e];
  int p = atomicAdd(&cur[d], 1);
  csr[rs[d] + p] = src[e];
}

// ---------------- merged prep: all 9 weight transposes + x0 cast ----------------
struct WTab {
  const float* src[NW];
  int K[NW];
  int N[NW];
  long long dstOff[NW];
  int tileStart[NW + 1];
  const float* x0;
  bf16_t* castDst;
  int castStart;
};

__global__ __launch_bounds__(256) void prep_all_kernel(WTab tab, bf16_t* __restrict__ WT) {
  int b = blockIdx.x;
  int t = threadIdx.x;
  if (b >= tab.castStart) {
    int i = (b - tab.castStart) * 256 + t;
    f32x4_t a = ((const f32x4_t*)tab.x0)[i * 2];
    f32x4_t bb = ((const f32x4_t*)tab.x0)[i * 2 + 1];
    bf16x8_t o;
#pragma unroll
    for (int j = 0; j < 4; ++j) { o[j] = (bf16_t)a[j]; o[4 + j] = (bf16_t)bb[j]; }
    ((bf16x8_t*)tab.castDst)[i] = o;
    return;
  }
  int wi = 0;
#pragma unroll
  for (int k = 1; k < NW; ++k)
    if (b >= tab.tileStart[k]) wi = k;
  int tt = b - tab.tileStart[wi];
  int K = tab.K[wi], N = tab.N[wi];
  int ntn = N >> 6;
  int n0 = (tt % ntn) * 64, k0 = (tt / ntn) * 64;
  const float* in = tab.src[wi];
  bf16_t* out = WT + tab.dstOff[wi];

  __shared__ float tile[64][65];
  for (int c = t; c < 1024; c += 256) {
    int r = c >> 4, col = (c & 15) * 4;
    f32x4_t v = *(const f32x4_t*)&in[(size_t)(k0 + r) * N + n0 + col];
#pragma unroll
    for (int j = 0; j < 4; ++j) tile[r][col + j] = v[j];
  }
  __syncthreads();
  for (int c = t; c < 512; c += 256) {
    int r = c >> 3, col = (c & 7) * 8;
    bf16x8_t v;
#pragma unroll
    for (int j = 0; j < 8; ++j) v[j] = (bf16_t)tile[col + j][r];
    *(bf16x8_t*)&out[(size_t)(n0 + r) * K + k0 + col] = v;
  }
}

// ---------------- standalone transpose+cast (fallback path) ----------------
__global__ __launch_bounds__(256) void transpose_cast_kernel(const float* __restrict__ in,
                                                             bf16_t* __restrict__ out,
                                                             int K, int N) {
  __shared__ float tile[64][65];
  int n0 = blockIdx.x * 64, k0 = blockIdx.y * 64;
  int t = threadIdx.x;
  for (int c = t; c < 1024; c += 256) {
    int r = c >> 4, col = (c & 15) * 4;
    f32x4_t v = *(const f32x4_t*)&in[(size_t)(k0 + r) * N + n0 + col];
#pragma unroll
    for (int j = 0; j < 4; ++j) tile[r][col + j] = v[j];
  }
  __syncthreads();
  for (int c = t; c < 512; c += 256) {
    int r = c >> 3, col = (c & 7) * 8;
    bf16x8_t v;
#pragma unroll
    for (int j = 0; j < 8; ++j) v[j] = (bf16_t)tile[col + j][r];
    *(bf16x8_t*)&out[(size_t)(n0 + r) * K + k0 + col] = v;
  }
}

__global__ __launch_bounds__(256) void cast_kernel(const float* __restrict__ in,
                                                   bf16_t* __restrict__ out) {
  int i = blockIdx.x * 256 + threadIdx.x;
  f32x4_t a = ((const f32x4_t*)in)[i * 2];
  f32x4_t b = ((const f32x4_t*)in)[i * 2 + 1];
  bf16x8_t o;
#pragma unroll
  for (int j = 0; j < 4; ++j) { o[j] = (bf16_t)a[j]; o[4 + j] = (bf16_t)b[j]; }
  ((bf16x8_t*)out)[i] = o;
}

// ------- layer-0 aggregation, d=256 -------
__global__ __launch_bounds__(64) void agg0_kernel(const bf16_t* __restrict__ x,
                                                  bf16_t* __restrict__ out,
                                                  const int* __restrict__ rs,
                                                  const int* __restrict__ csr) {
  int t = threadIdx.x;
  int node = blockIdx.x * 2 + (t >> 5);
  int c = t & 31;
  const bf16x8_t* xv = (const bf16x8_t*)x;
  bf16x8_t self = xv[(size_t)node * 32 + c];
  float acc[8];
#pragma unroll
  for (int j = 0; j < 8; ++j) acc[j] = (float)self[j];
  int e0 = rs[node], e1 = rs[node + 1];
  int e = e0;
  for (; e + 4 <= e1; e += 4) {
    int s0 = csr[e], s1 = csr[e + 1], s2 = csr[e + 2], s3 = csr[e + 3];
    bf16x8_t v0 = xv[(size_t)s0 * 32 + c];
    bf16x8_t v1 = xv[(size_t)s1 * 32 + c];
    bf16x8_t v2 = xv[(size_t)s2 * 32 + c];
    bf16x8_t v3 = xv[(size_t)s3 * 32 + c];
#pragma unroll
    for (int j = 0; j < 8; ++j)
      acc[j] += (float)v0[j] + (float)v1[j] + (float)v2[j] + (float)v3[j];
  }
  for (; e < e1; ++e) {
    bf16x8_t v = xv[(size_t)csr[e] * 32 + c];
#pragma unroll
    for (int j = 0; j < 8; ++j) acc[j] += (float)v[j];
  }
  bf16x8_t o;
#pragma unroll
  for (int j = 0; j < 8; ++j) o[j] = (bf16_t)acc[j];
  ((bf16x8_t*)out)[(size_t)node * 32 + c] = o;
}

// ------- aggregation over tiled activations, XCD-pinned tiles (validated r8) -------
__global__ __launch_bounds__(256) void agg_tiled_kernel(const bf16_t* __restrict__ x,
                                                        bf16_t* __restrict__ out,
                                                        const int* __restrict__ rs,
                                                        const int* __restrict__ csr,
                                                        const float* __restrict__ bias,
                                                        int relu, int tmask, int tshift) {
  int t = threadIdx.x;
  int tile = blockIdx.x & tmask;
  int ng = blockIdx.x >> tshift;
  int node = ng * 8 + (t >> 5);
  int c = t & 31;
  size_t tb = (size_t)tile * (NN * 32);
  const bf16x8_t* xv = (const bf16x8_t*)x + tb;
  bf16x8_t self = xv[node * 32 + c];
  float acc[8];
#pragma unroll
  for (int j = 0; j < 8; ++j) acc[j] = (float)self[j];
  int e0 = rs[node], e1 = rs[node + 1];
  int e = e0;
  for (; e + 4 <= e1; e += 4) {
    int s0 = csr[e], s1 = csr[e + 1], s2 = csr[e + 2], s3 = csr[e + 3];
    bf16x8_t v0 = xv[s0 * 32 + c];
    bf16x8_t v1 = xv[s1 * 32 + c];
    bf16x8_t v2 = xv[s2 * 32 + c];
    bf16x8_t v3 = xv[s3 * 32 + c];
#pragma unroll
    for (int j = 0; j < 8; ++j)
      acc[j] += (float)v0[j] + (float)v1[j] + (float)v2[j] + (float)v3[j];
  }
  for (; e < e1; ++e) {
    bf16x8_t v = xv[csr[e] * 32 + c];
#pragma unroll
    for (int j = 0; j < 8; ++j) acc[j] += (float)v[j];
  }
  if (bias) {
    const float* bp = bias + tile * 256 + c * 8;
    f32x4_t b0 = *(const f32x4_t*)bp;
    f32x4_t b1 = *(const f32x4_t*)(bp + 4);
#pragma unroll
    for (int j = 0; j < 4; ++j) { acc[j] += b0[j]; acc[4 + j] += b1[j]; }
  }
  if (relu) {
#pragma unroll
    for (int j = 0; j < 8; ++j) acc[j] = fmaxf(acc[j], 0.f);
  }
  bf16x8_t o;
#pragma unroll
  for (int j = 0; j < 8; ++j) o[j] = (bf16_t)acc[j];
  ((bf16x8_t*)out + tb)[node * 32 + c] = o;
}

// ------- GEMM: C = A(tiled) @ Bt^T + bias [+relu]; M == NN fixed -------
// 1-D grid, XCD-banded swizzle: xcd = bid%8 owns a contiguous 8-m-row band (4 MB of A =
// one XCD L2) x all n; B shared by co-resident m-rows. Shortens the vmcnt(0) drain by
// converting staging-load misses into L2 hits.
// CMODE 0: bf16 tiled output. CMODE 1: head f32 split output (mean|var + separate biases).
template <int CMODE>
__global__ __launch_bounds__(256, 2) void gemm_bt_kernel(
    const bf16_t* __restrict__ A, const bf16_t* __restrict__ Bt,
    const float* __restrict__ bias, const float* __restrict__ biasB,
    void* __restrict__ Cv, int N, int K, int relu, int nbxShift) {
  __shared__ __align__(16) bf16_t lA[128 * 32];
  __shared__ __align__(16) bf16_t lB[128 * 32];
  const int tid = threadIdx.x;
  const int lane = tid & 63;
  const int wave = tid >> 6;
  const int wm64 = (wave & 1) * 64;
  const int wn64 = (wave >> 1) * 64;
  const int row16 = lane & 15;
  const int quad = lane >> 4;

  const int bid = blockIdx.x;
  const int xcd = bid & 7;
  const int rank = bid >> 3;
  const int bn = rank & ((1 << nbxShift) - 1);
  const int mPer = gridDim.x >> (3 + nbxShift);
  const int bm = xcd * mPer + (rank >> nbxShift);
  const size_t m0 = (size_t)bm * 128;
  const size_t n0 = (size_t)bn * 128;

  f32x4_t acc[4][4];
#pragma unroll
  for (int i = 0; i < 4; ++i)
#pragma unroll
    for (int j = 0; j < 4; ++j)
#pragma unroll
      for (int r = 0; r < 4; ++r) acc[i][j][r] = 0.f;

  const bf16_t* Bbase = Bt + n0 * K;
  const int r0 = tid >> 2;
  const int r1 = (tid + 256) >> 2;
  const int kc = (tid & 3) * 8;

  for (int kt = 0; kt < K; kt += 32) {
    const bf16_t* Ab = A + ((size_t)(kt >> 8)) * (NN * 256) + (kt & 255) + kc;
    async16(&lA[tid * 8], Ab + (m0 + r0) * 256);
    async16(&lA[(tid + 256) * 8], Ab + (m0 + r1) * 256);
    async16(&lB[tid * 8], Bbase + (size_t)r0 * K + kt + kc);
    async16(&lB[(tid + 256) * 8], Bbase + (size_t)r1 * K + kt + kc);
    __syncthreads();
    bf16x8_t af[4], bfr[4];
#pragma unroll
    for (int i = 0; i < 4; ++i)
      af[i] = *(const bf16x8_t*)&lA[(wm64 + i * 16 + row16) * 32 + quad * 8];
#pragma unroll
    for (int i = 0; i < 4; ++i)
      bfr[i] = *(const bf16x8_t*)&lB[(wn64 + i * 16 + row16) * 32 + quad * 8];
#pragma unroll
    for (int i = 0; i < 4; ++i)
#pragma unroll
      for (int j = 0; j < 4; ++j)
        acc[i][j] = __builtin_amdgcn_mfma_f32_16x16x32_bf16(af[i], bfr[j], acc[i][j], 0, 0, 0);
    __syncthreads();
  }

  // C/D layout: col = lane&15, row = quad*4 + reg  [verified m89/m91]
#pragma unroll
  for (int i = 0; i < 4; ++i) {
    size_t row = m0 + wm64 + i * 16 + quad * 4;
#pragma unroll
    for (int j = 0; j < 4; ++j) {
      int col = (int)n0 + wn64 + j * 16 + row16;
      if (CMODE == 0) {
        float b = bias ? bias[col] : 0.f;
        size_t cb = ((size_t)(col >> 8)) * (NN * 256) + (col & 255);
#pragma unroll
        for (int r = 0; r < 4; ++r) {
          float o = acc[i][j][r] + b;
          if (relu) o = fmaxf(o, 0.f);
          ((bf16_t*)Cv)[cb + (row + r) * 256] = (bf16_t)o;
        }
      } else {
        int sel = col >> 7;
        int c2 = col & 127;
        float b = sel ? biasB[c2] : bias[c2];
        float* dstp = (float*)Cv + (size_t)(1 + sel) * NN * LL + c2;
#pragma unroll
        for (int r = 0; r < 4; ++r) {
          dstp[(row + r) * LL] = acc[i][j][r] + b;
        }
      }
    }
  }
}

// ---------------- z = mean + var*eps (f32) ----------------
__global__ __launch_bounds__(256) void reparam_kernel(const float* __restrict__ mean,
                                                      const float* __restrict__ var,
                                                      const float* __restrict__ eps,
                                                      float* __restrict__ z) {
  int i = blockIdx.x * 256 + threadIdx.x;
  f32x4_t m = ((const f32x4_t*)mean)[i];
  f32x4_t v = ((const f32x4_t*)var)[i];
  f32x4_t e = ((const f32x4_t*)eps)[i];
  f32x4_t o;
#pragma unroll
  for (int j = 0; j < 4; ++j) o[j] = m[j] + v[j] * e[j];
  ((f32x4_t*)z)[i] = o;
}

extern "C" void kernel_launch(void* const* d_in, const int* in_sizes, int n_in,
                              void* d_out, int out_size, void* d_ws, size_t ws_size,
                              hipStream_t stream) {
  (void)in_sizes; (void)n_in; (void)out_size;
  const float* x0 = (const float*)d_in[0];
  const int* ei = (const int*)d_in[1];
  const int* src = ei;
  const int* dst = ei + EE;
  const float* w1[4] = {(const float*)d_in[2], (const float*)d_in[6],
                        (const float*)d_in[10], (const float*)d_in[14]};
  const float* b1[4] = {(const float*)d_in[3], (const float*)d_in[7],
                        (const float*)d_in[11], (const float*)d_in[15]};
  const float* w2[4] = {(const float*)d_in[4], (const float*)d_in[8],
                        (const float*)d_in[12], (const float*)d_in[16]};
  const float* b2[4] = {(const float*)d_in[5], (const float*)d_in[9],
                        (const float*)d_in[13], (const float*)d_in[17]};
  const float* wm = (const float*)d_in[18];
  const float* bm = (const float*)d_in[19];
  const float* wv = (const float*)d_in[20];
  const float* bv = (const float*)d_in[21];
  const float* eps = (const float*)d_in[22];
  float* out = (float*)d_out;

  char* ws = (char*)d_ws;
  bf16_t* B0 = (bf16_t*)(ws);
  bf16_t* B1 = (bf16_t*)(ws + 33554432);
  bf16_t* WT = (bf16_t*)(ws + 67108864);

  // Per-weight WT slot offsets (bf16 elems), order: w1_0,w2_0,w1_1,w2_1,w1_2,w2_2,w1_3,w2_3,wm,wv
  const long long soff[NW] = {0LL, 524288LL, 4718592LL, 8912896LL, 13107200LL,
                              17301504LL, 21495808LL, 23592960LL, 24641536LL, 24772608LL};
  const size_t wtBytesFull = 24903680ULL * 2ULL;          // 49.8 MB
  const size_t needFull = 67108864ULL + wtBytesFull + 2097152ULL;
  bool full = ws_size >= needFull;

  size_t csrBase = full ? (67108864ULL + wtBytesFull) : 75497472ULL;
  int* deg = (int*)(ws + csrBase);
  int* cur = deg + 8192;
  int* rs = deg + 16384;
  int* csr = deg + 16384 + 8200;

  auto AGG = [&](const bf16_t* in, bf16_t* outp, int d, const float* bias, int relu) {
    int ntiles = d >> 8;
    int tshift = (ntiles == 8) ? 3 : 2;
    agg_tiled_kernel<<<(NN / 8) * ntiles, 256, 0, stream>>>(in, outp, rs, csr, bias, relu,
                                                            ntiles - 1, tshift);
  };

  if (full) {
    // ---- merged prep: all transposes + x0 cast in one dispatch ----
    WTab tab;
    const float* srcs[NW] = {w1[0], w2[0], w1[1], w2[1], w1[2], w2[2], w1[3], w2[3], wm, wv};
    const int Ks[NW] = {TT, HH, HH, HH, HH, HH, HH, OO, OO, OO};
    const int Ns[NW] = {HH, HH, HH, HH, HH, HH, OO, OO, LL, LL};
    int cum = 0;
    for (int i = 0; i < NW; ++i) {
      tab.src[i] = srcs[i];
      tab.K[i] = Ks[i];
      tab.N[i] = Ns[i];
      tab.dstOff[i] = soff[i];
      tab.tileStart[i] = cum;
      cum += (Ns[i] >> 6) * (Ks[i] >> 6);
    }
    tab.tileStart[NW] = cum;
    tab.castStart = cum;
    tab.x0 = x0;
    tab.castDst = B0;
    int totalBlocks = cum + (NN * TT / 8) / 256;
    prep_all_kernel<<<totalBlocks, 256, 0, stream>>>(tab, WT);

    hipMemsetAsync(deg, 0, 2 * 8192 * sizeof(int), stream);
    count_deg_kernel<<<EE / 256, 256, 0, stream>>>(dst, deg);
    scan_kernel<<<1, 1024, 0, stream>>>(deg, rs);
    fill_csr_kernel<<<EE / 256, 256, 0, stream>>>(src, dst, rs, cur, csr);

    auto G = [&](const bf16_t* A, int wi, const float* bias, bf16_t* C, int Nn, int K, int relu) {
      int nbx = Nn / 128;
      int shift = __builtin_ctz(nbx);
      gemm_bt_kernel<0><<<nbx * (NN / 128), 256, 0, stream>>>(
          A, WT + soff[wi], bias, nullptr, (void*)C, Nn, K, relu, shift);
    };

    agg0_kernel<<<NN / 2, 64, 0, stream>>>(B0, B1, rs, csr);
    G(B1, 0, b1[0], B0, HH, TT, 1);
    G(B0, 1, b2[0], B1, HH, HH, 1);
    AGG(B1, B0, HH, nullptr, 0);
    G(B0, 2, b1[1], B1, HH, HH, 1);
    G(B1, 3, b2[1], B0, HH, HH, 1);
    AGG(B0, B1, HH, nullptr, 0);
    G(B1, 4, b1[2], B0, HH, HH, 1);
    G(B0, 5, b2[2], B1, HH, HH, 1);
    // Layer 3 reordered: Y = x3 @ w1_3 (no bias); agg 1024-d fused b1_3+relu; then w2_3.
    G(B1, 6, nullptr, B0, OO, HH, 0);
    AGG(B0, B1, OO, b1[3], 1);
    G(B1, 7, b2[3], B0, OO, OO, 0);
    // Heads: wm|wv adjacent -> one N=256 GEMM, f32 split epilogue, direct bm/bv
    gemm_bt_kernel<1><<<2 * (NN / 128), 256, 0, stream>>>(
        B0, WT + soff[8], bm, bv, (void*)out, 256, OO, 0, 1);
  } else {
    // ---- fallback: interleaved scheme (shared 8.4MB WT) ----
    hipMemsetAsync(deg, 0, 2 * 8192 * sizeof(int), stream);
    count_deg_kernel<<<EE / 256, 256, 0, stream>>>(dst, deg);
    scan_kernel<<<1, 1024, 0, stream>>>(deg, rs);
    fill_csr_kernel<<<EE / 256, 256, 0, stream>>>(src, dst, rs, cur, csr);

    auto T = [&](const float* w, int K, int Nn, bf16_t* dstw) {
      transpose_cast_kernel<<<dim3(Nn / 64, K / 64), 256, 0, stream>>>(w, dstw, K, Nn);
    };
    auto G = [&](const bf16_t* A, const float* bias, bf16_t* C, int Nn, int K, int relu) {
      int nbx = Nn / 128;
      int shift = __builtin_ctz(nbx);
      gemm_bt_kernel<0><<<nbx * (NN / 128), 256, 0, stream>>>(
          A, WT, bias, nullptr, (void*)C, Nn, K, relu, shift);
    };

    cast_kernel<<<(NN * TT / 8) / 256, 256, 0, stream>>>(x0, B0);
    agg0_kernel<<<NN / 2, 64, 0, stream>>>(B0, B1, rs, csr);
    T(w1[0], TT, HH, WT); G(B1, b1[0], B0, HH, TT, 1);
    T(w2[0], HH, HH, WT); G(B0, b2[0], B1, HH, HH, 1);
    AGG(B1, B0, HH, nullptr, 0);
    T(w1[1], HH, HH, WT); G(B0, b1[1], B1, HH, HH, 1);
    T(w2[1], HH, HH, WT); G(B1, b2[1], B0, HH, HH, 1);
    AGG(B0, B1, HH, nullptr, 0);
    T(w1[2], HH, HH, WT); G(B1, b1[2], B0, HH, HH, 1);
    T(w2[2], HH, HH, WT); G(B0, b2[2], B1, HH, HH, 1);
    T(w1[3], HH, OO, WT); G(B1, nullptr, B0, OO, HH, 0);
    AGG(B0, B1, OO, b1[3], 1);
    T(w2[3], OO, OO, WT); G(B1, b2[3], B0, OO, OO, 0);
    T(wm, OO, LL, WT);
    T(wv, OO, LL, WT + (size_t)LL * OO);
    gemm_bt_kernel<1><<<2 * (NN / 128), 256, 0, stream>>>(
        B0, WT, bm, bv, (void*)out, 256, OO, 0, 1);
  }

  reparam_kernel<<<(NN * LL / 4) / 256, 256, 0, stream>>>(
      out + (size_t)NN * LL, out + (size_t)2 * NN * LL, eps, out);
}